// Round 12
// baseline (724.526 us; speedup 1.0000x reference)
//
#include <hip/hip_runtime.h>
#include <stdint.h>

#define NPIX 4096
#define CDIM 512

typedef _Float16 hv8 __attribute__((ext_vector_type(8)));
typedef float f32x4 __attribute__((ext_vector_type(4)));

__device__ __forceinline__ void lds_direct16(const _Float16* g, _Float16* l) {
    __builtin_amdgcn_global_load_lds(
        (const __attribute__((address_space(1))) void*)g,
        (__attribute__((address_space(3))) void*)l, 16, 0, 0);
}

// ---------------- weight fp32 -> fp16 ----------------
__global__ void cvt_w(const float* __restrict__ s0, const float* __restrict__ s1,
                      const float* __restrict__ s2, const float* __restrict__ s3,
                      _Float16* __restrict__ d0, _Float16* __restrict__ d1,
                      _Float16* __restrict__ d2, _Float16* __restrict__ d3) {
    int i = blockIdx.x * 256 + threadIdx.x;
    d0[i] = (_Float16)s0[i];
    d1[i] = (_Float16)s1[i];
    d2[i] = (_Float16)s2[i];
    d3[i] = (_Float16)s3[i];
}

// ---------------- groupnorm stats: one block per (b,g) ----------------
__global__ void stats_kernel(const float* __restrict__ x, float* __restrict__ stats) {
    int idx = blockIdx.x;
    const float4* base = (const float4*)(x + (long)idx * 16 * NPIX);
    int tid = threadIdx.x;
    float s = 0.f, sq = 0.f;
    for (int it = 0; it < 64; ++it) {
        float4 f = base[it * 256 + tid];
        s  += f.x + f.y + f.z + f.w;
        sq += f.x * f.x + f.y * f.y + f.z * f.z + f.w * f.w;
    }
    __shared__ float rs[256], rq[256];
    rs[tid] = s; rq[tid] = sq;
    __syncthreads();
    for (int st = 128; st > 0; st >>= 1) {
        if (tid < st) { rs[tid] += rs[tid + st]; rq[tid] += rq[tid + st]; }
        __syncthreads();
    }
    if (tid == 0) {
        float mean = rs[0] * (1.0f / 65536.0f);
        float var  = rq[0] * (1.0f / 65536.0f) - mean * mean;
        stats[idx * 2]     = mean;
        stats[idx * 2 + 1] = rsqrtf(var + 1e-6f);
    }
}

// ---------------- normalize + transpose: hT[b][n][c] = GN(x)[b][c][n] ----------------
__global__ void normT_kernel(const float* __restrict__ x, const float* __restrict__ stats,
                             const float* __restrict__ gamma, const float* __restrict__ beta,
                             _Float16* __restrict__ hT) {
    int b = blockIdx.z, c0 = blockIdx.x * 32, n0 = blockIdx.y * 32;
    int tid = threadIdx.x;
    __shared__ float t[32][33];
    int cl = tid >> 5;
    int nl = tid & 31;
    for (int r = 0; r < 4; ++r)
        t[r * 8 + cl][nl] = x[(long)b * CDIM * NPIX + (long)(c0 + r * 8 + cl) * NPIX + n0 + nl];
    __syncthreads();
    for (int r = 0; r < 4; ++r) {
        int nr = r * 8 + cl;
        int c = c0 + nl;
        float m    = stats[(b * 32 + (c >> 4)) * 2];
        float rstd = stats[(b * 32 + (c >> 4)) * 2 + 1];
        float val = (t[nl][nr] - m) * rstd * gamma[c] + beta[c];
        hT[(long)b * NPIX * CDIM + (long)(n0 + nr) * CDIM + c] = (_Float16)val;
    }
}

// ---------------- bt-form GEMM: D[M][N] = A[M][K] * BT[N][K]^T ----------------
template<int EPI>
__launch_bounds__(256, 2)
__global__ void gemm_bt_kernel(const _Float16* __restrict__ A, const _Float16* __restrict__ BT,
                               void* __restrict__ D, const float* __restrict__ bias,
                               const float* __restrict__ resid,
                               int M, int N, int K,
                               long aBatch, long bBatch, long dBatch, long rBatch) {
    const int b = blockIdx.z;
    A  += (long)b * aBatch;
    BT += (long)b * bBatch;
    const int m0 = blockIdx.y * 128;
    const int n0 = blockIdx.x * 128;
    const int tid = threadIdx.x;
    const int l = tid & 63;
    const int w = tid >> 6;
    const int wm = (w >> 1) * 64;
    const int wn = (w & 1) * 64;
    const int lr = l & 15;
    const int lk = l >> 4;
    __shared__ __align__(16) _Float16 As[128 * 32];
    __shared__ __align__(16) _Float16 Bs[128 * 32];
    f32x4 acc[4][4] = {};
    const int nK = K >> 5;
    for (int kt = 0; kt < nK; ++kt) {
        const int kb = kt * 32;
#pragma unroll
        for (int c = 0; c < 2; ++c) {
            int chunk = c * 256 + tid;
            int row = chunk >> 2;
            int k8 = (chunk & 3) * 8;
            _Float16* ldsA = As + (size_t)(c * 256 + (tid & ~63)) * 8;
            _Float16* ldsB = Bs + (size_t)(c * 256 + (tid & ~63)) * 8;
            lds_direct16(A  + (long)(m0 + row) * K + kb + k8, ldsA);
            lds_direct16(BT + (long)(n0 + row) * K + kb + k8, ldsB);
        }
        __syncthreads();
        hv8 af[4], bfr[4];
#pragma unroll
        for (int mi = 0; mi < 4; ++mi)
            af[mi] = *(const hv8*)(As + (size_t)(wm + mi * 16 + lr) * 32 + lk * 8);
#pragma unroll
        for (int ni = 0; ni < 4; ++ni)
            bfr[ni] = *(const hv8*)(Bs + (size_t)(wn + ni * 16 + lr) * 32 + lk * 8);
#pragma unroll
        for (int mi = 0; mi < 4; ++mi)
#pragma unroll
            for (int ni = 0; ni < 4; ++ni)
                acc[mi][ni] = __builtin_amdgcn_mfma_f32_16x16x32_f16(af[mi], bfr[ni], acc[mi][ni], 0, 0, 0);
        __syncthreads();
    }
#pragma unroll
    for (int mi = 0; mi < 4; ++mi)
#pragma unroll
        for (int ni = 0; ni < 4; ++ni)
#pragma unroll
            for (int r = 0; r < 4; ++r) {
                int row = m0 + wm + mi * 16 + lk * 4 + r;
                int col = n0 + wn + ni * 16 + lr;
                float val = acc[mi][ni][r];
                if (EPI == 0) {
                    ((_Float16*)D)[(long)b * dBatch + (long)row * N + col] = (_Float16)(val + bias[col]);
                } else if (EPI == 1) {
                    ((_Float16*)D)[(long)b * dBatch + (long)row * N + col] = (_Float16)(val + bias[row]);
                } else {
                    long idx = (long)row * N + col;
                    ((float*)D)[(long)b * dBatch + idx] =
                        val + bias[row] + resid[(long)b * rBatch + idx];
                }
            }
}

// ---------------- flash attention v12: 2 blocks/CU ----------------
// v11 per-block structure (i-tile 64, j-tile 32, one barrier/step, PV deferred
// one step, parity-disjoint ps, K LDS dbuf, V regs single-buffered WAR-safe,
// counted vmcnt(4)) with j-split 4: grid 512 -> 2 co-resident blocks per CU
// (LDS 76.7KB x2 fits 160KB; VGPR 116 <= 128 -> 4 waves/SIMD). Each (batch,
// j-quarter) pins to one XCD: K+V quarter = 2MB, L2-resident. TLP hides the
// per-step barrier-drain latency that one block leaves exposed.
__launch_bounds__(512, 4)
__global__ void attn_kernel(const _Float16* __restrict__ qT, const _Float16* __restrict__ kT,
                            const _Float16* __restrict__ v,
                            _Float16* __restrict__ p0, _Float16* __restrict__ p1,
                            _Float16* __restrict__ p2, _Float16* __restrict__ p3,
                            float* __restrict__ lbuf) {
    __shared__ __align__(16) _Float16 Ks[2][32 * 512];   // 64 KB, rows 1 KB, XOR (j&7)<<4
    __shared__ __align__(16) char ps[2][64 * 80];        // 10 KB, 80 B rows
    __shared__ float red[8][64];
    __shared__ float redt[64];

    const int g = blockIdx.x;                        // 0..511
    const int xcd = g & 7;                           // = (batch, jquarter) combo
    const int batch = xcd >> 2;
    const int jq4 = xcd & 3;
    const int itile = g >> 3;                        // 0..63
    const int i0 = itile * 64;
    const int jbase = jq4 * 1024;

    const int tid = threadIdx.x;
    const int l = tid & 63, w = tid >> 6;
    const int lr = l & 15, lk = l >> 4;
    const int iq = w >> 1, jq = w & 1;               // QK: rows iq*16, cols jq*16

    const _Float16* qb = qT + (long)batch * NPIX * CDIM;
    const _Float16* kb = kT + (long)batch * NPIX * CDIM;
    const _Float16* vb = v  + (long)batch * CDIM * NPIX;

    // Q fragments: rows i0 + iq*16 + lr, all 16 k-chunks (64 VGPR)
    hv8 af[16];
    {
        const _Float16* qr = qb + (long)(i0 + iq * 16 + lr) * CDIM + lk * 8;
#pragma unroll
        for (int kk = 0; kk < 16; ++kk)
            af[kk] = *(const hv8*)(qr + kk * 32);
    }

    f32x4 oacc[4][4] = {};   // rows mi*16+lk*4+r, cols w*64+ni*16+lr (AGPR)
    float lsum[4] = {};
    hv8 vf[4];               // V(t): wave-unique c-range w*64, 32 VGPR

    const _Float16* vptr = vb + (long)(w * 64 + lr) * NPIX + jbase + lk * 8;
    const float scale = 0.044194173824159216f;   // 1/sqrt(512)

// stage K tile JT (32 rows) into Ks[BUF]; 4 instrs/thread, source col pre-swizzled
#define STAGE(BUF, JT)                                                               \
    {                                                                                \
        const long j0s = (long)jbase + (JT) * 32;                                    \
        _Float16* kd = Ks[BUF];                                                      \
        _Pragma("unroll")                                                            \
        for (int q = 0; q < 4; ++q) {                                                \
            int row = q * 8 + w;                                                     \
            int cc = l ^ (row & 7);                                                  \
            lds_direct16(kb + (j0s + row) * CDIM + cc * 8, kd + row * 512);          \
        }                                                                            \
    }

// load V fragments for tile JT (4 x b128 from L2; wave-unique c-range)
#define VLOAD(JT)                                                                    \
    {                                                                                \
        _Pragma("unroll")                                                            \
        for (int ni = 0; ni < 4; ++ni)                                               \
            vf[ni] = *(const hv8*)(vptr + (long)ni * (16 * NPIX) + (JT) * 32);       \
    }

// QK(JT) -> exp -> ps[CUR]
#define QKEXP(CUR)                                                                   \
    {                                                                                \
        const char* kbase = (const char*)Ks[CUR];                                    \
        f32x4 sa = {}, sb = {};                                                      \
        const int jj = jq * 16 + lr;                                                 \
        const uint32_t sw = (uint32_t)((jj & 7) << 4);                               \
        _Pragma("unroll")                                                            \
        for (int kk = 0; kk < 8; ++kk) {                                             \
            hv8 b0 = *(const hv8*)(kbase + (((uint32_t)(jj * 1024 + (2 * kk) * 64 + lk * 16)) ^ sw));     \
            sa = __builtin_amdgcn_mfma_f32_16x16x32_f16(af[2 * kk], b0, sa, 0, 0, 0);                     \
            hv8 b1 = *(const hv8*)(kbase + (((uint32_t)(jj * 1024 + (2 * kk + 1) * 64 + lk * 16)) ^ sw)); \
            sb = __builtin_amdgcn_mfma_f32_16x16x32_f16(af[2 * kk + 1], b1, sb, 0, 0, 0);                 \
        }                                                                            \
        sa += sb;                                                                    \
        _Pragma("unroll")                                                            \
        for (int r = 0; r < 4; ++r) {                                                \
            float p = __expf(sa[r] * scale);                                         \
            lsum[r] += p;                                                            \
            int i = iq * 16 + lk * 4 + r;                                            \
            int j2 = jq * 16 + lr;                                                   \
            *(_Float16*)(ps[CUR] + i * 80 + j2 * 2) = (_Float16)p;                   \
        }                                                                            \
    }

// PV of the PREVIOUS step: ps[PRV] x vf (holding V(t-1))
#define PVSTEP(PRV)                                                                  \
    {                                                                                \
        _Pragma("unroll")                                                            \
        for (int mi = 0; mi < 4; ++mi) {                                             \
            int i2 = mi * 16 + lr;                                                   \
            hv8 pa = *(const hv8*)(ps[PRV] + i2 * 80 + lk * 16);                     \
            _Pragma("unroll")                                                        \
            for (int ni = 0; ni < 4; ++ni)                                           \
                oacc[mi][ni] = __builtin_amdgcn_mfma_f32_16x16x32_f16(pa, vf[ni], oacc[mi][ni], 0, 0, 0); \
        }                                                                            \
    }

// counted end barrier: retires the 4 K-stage loads, keeps the 4 V loads in flight
#define ENDBAR(N)                                                                    \
    __builtin_amdgcn_sched_barrier(0);                                               \
    asm volatile("s_waitcnt vmcnt(" #N ") lgkmcnt(0)" ::: "memory");                 \
    __builtin_amdgcn_s_barrier();                                                    \
    __builtin_amdgcn_sched_barrier(0);

// CUR = compile-time parity of JT (passed as literal).
#define STEP(JT, CUR)                                                                \
    {                                                                                \
        if ((JT) < 31) STAGE((CUR) ^ 1, (JT) + 1)                                    \
        __builtin_amdgcn_sched_barrier(0);                                           \
        __builtin_amdgcn_s_setprio(1);                                               \
        QKEXP(CUR)                                                                   \
        PVSTEP((CUR) ^ 1)                                                            \
        __builtin_amdgcn_s_setprio(0);                                               \
        __builtin_amdgcn_sched_barrier(0);                                           \
        VLOAD(JT)                                                                    \
        ENDBAR(4)                                                                    \
    }

    // prologue: K(0) staged and drained
    STAGE(0, 0)
    __builtin_amdgcn_sched_barrier(0);
    asm volatile("s_waitcnt vmcnt(0)" ::: "memory");
    __builtin_amdgcn_s_barrier();
    __builtin_amdgcn_sched_barrier(0);

    // step 0: no PV yet; V(0) loaded after QK
    STAGE(1, 1)
    __builtin_amdgcn_s_setprio(1);
    QKEXP(0)
    __builtin_amdgcn_s_setprio(0);
    VLOAD(0)
    ENDBAR(4)

    // steady: steps 1..30 in pairs, then 31
    for (int jt = 1; jt < 31; jt += 2) {
        STEP(jt,     1)
        STEP(jt + 1, 0)
    }
    STEP(31, 1)

    // epilogue: PV(31) -- drain the last V loads first
    asm volatile("s_waitcnt vmcnt(0)" ::: "memory");
    __builtin_amdgcn_sched_barrier(0);
    PVSTEP(1)

    // ---- row-sum reduce: over lr (16 lanes), then over the jq wave-pair ----
#pragma unroll
    for (int m = 1; m <= 8; m <<= 1)
#pragma unroll
        for (int r = 0; r < 4; ++r)
            lsum[r] += __shfl_xor(lsum[r], m, 64);
    if (lr == 0)
#pragma unroll
        for (int r = 0; r < 4; ++r)
            red[w][iq * 16 + lk * 4 + r] = lsum[r];
    __syncthreads();
    if (tid < 64) {
        int iq2 = tid >> 4;
        float lv = red[iq2 * 2][tid] + red[iq2 * 2 + 1][tid];
        redt[tid] = 1.0f / lv;
        lbuf[jq4 * 8192 + batch * NPIX + i0 + tid] = lv;
    }
    __syncthreads();

    // ---- store normalized per-quarter partial O (fp16) ----
    _Float16* dsth = (jq4 == 0 ? p0 : jq4 == 1 ? p1 : jq4 == 2 ? p2 : p3)
                   + (long)batch * NPIX * CDIM;
#pragma unroll
    for (int mi = 0; mi < 4; ++mi)
#pragma unroll
        for (int r = 0; r < 4; ++r) {
            int row = mi * 16 + lk * 4 + r;
            float rv = redt[row];
#pragma unroll
            for (int ni = 0; ni < 4; ++ni) {
                int c = w * 64 + ni * 16 + lr;
                dsth[(long)(i0 + row) * CDIM + c] = (_Float16)(oacc[mi][ni][r] * rv);
            }
        }
#undef STEP
#undef ENDBAR
#undef PVSTEP
#undef QKEXP
#undef VLOAD
#undef STAGE
}

// ---------------- combine: out = sum_q O_q * l_q / sum_q l_q ----------------
__global__ void combine_kernel(const _Float16* __restrict__ p0, const _Float16* __restrict__ p1,
                               const _Float16* __restrict__ p2, const _Float16* __restrict__ p3,
                               const float* __restrict__ lbuf, _Float16* __restrict__ out) {
    long g = (long)blockIdx.x * 256 + threadIdx.x;
    long base = g * 8;
    int rowg = (int)(g >> 6);                 // b*4096 + n
    float l0 = lbuf[rowg], l1 = lbuf[8192 + rowg];
    float l2 = lbuf[16384 + rowg], l3 = lbuf[24576 + rowg];
    float inv = 1.0f / (l0 + l1 + l2 + l3);
    float w0 = l0 * inv, w1 = l1 * inv, w2 = l2 * inv, w3 = l3 * inv;
    hv8 a = *(const hv8*)(p0 + base);
    hv8 b = *(const hv8*)(p1 + base);
    hv8 c = *(const hv8*)(p2 + base);
    hv8 d = *(const hv8*)(p3 + base);
    hv8 o;
#pragma unroll
    for (int i = 0; i < 8; ++i)
        o[i] = (_Float16)((float)a[i] * w0 + (float)b[i] * w1
                        + (float)c[i] * w2 + (float)d[i] * w3);
    *(hv8*)(out + base) = o;
}

extern "C" void kernel_launch(void* const* d_in, const int* in_sizes, int n_in,
                              void* d_out, int out_size, void* d_ws, size_t ws_size,
                              hipStream_t stream) {
    const float* x     = (const float*)d_in[0];
    const float* gamma = (const float*)d_in[1];
    const float* beta  = (const float*)d_in[2];
    const float* wq    = (const float*)d_in[3];
    const float* bq    = (const float*)d_in[4];
    const float* wk    = (const float*)d_in[5];
    const float* bk    = (const float*)d_in[6];
    const float* wv    = (const float*)d_in[7];
    const float* bv    = (const float*)d_in[8];
    const float* wo    = (const float*)d_in[9];
    const float* bo    = (const float*)d_in[10];
    float* out = (float*)d_out;

    char* ws = (char*)d_ws;
    float* stats = (float*)ws;
    _Float16* wqb = (_Float16*)(ws + 1024);
    _Float16* wkb = wqb + 262144;
    _Float16* wvb = wkb + 262144;
    _Float16* wob = wvb + 262144;
    _Float16* hT  = wob + 262144;
    const long TSZ = (long)2 * NPIX * CDIM;
    _Float16* qT = hT + TSZ;
    _Float16* kT = qT + TSZ;
    _Float16* vv = kT + TSZ;
    _Float16* oT = vv + TSZ;
    float* lbuf = (float*)(oT + TSZ);        // 4 quarters x 8192 rows (128 KB)

    // q2/q3 partials live in d_out (16 MB, exactly 2 x 8MB fp16), overwritten
    // later by the final GEMM -- combine reads them first (stream-ordered).
    _Float16* pq2 = (_Float16*)d_out;
    _Float16* pq3 = pq2 + TSZ;

    cvt_w<<<dim3(1024), dim3(256), 0, stream>>>(wq, wk, wv, wo, wqb, wkb, wvb, wob);
    stats_kernel<<<dim3(64), dim3(256), 0, stream>>>(x, stats);
    normT_kernel<<<dim3(16, 128, 2), dim3(256), 0, stream>>>(x, stats, gamma, beta, hT);

    const long NC = (long)NPIX * CDIM;
    gemm_bt_kernel<0><<<dim3(4, 32, 2), dim3(256), 0, stream>>>(
        hT, wqb, (void*)qT, bq, nullptr, NPIX, CDIM, CDIM, NC, 0L, NC, 0L);
    gemm_bt_kernel<0><<<dim3(4, 32, 2), dim3(256), 0, stream>>>(
        hT, wkb, (void*)kT, bk, nullptr, NPIX, CDIM, CDIM, NC, 0L, NC, 0L);
    gemm_bt_kernel<1><<<dim3(32, 4, 2), dim3(256), 0, stream>>>(
        wvb, hT, (void*)vv, bv, nullptr, CDIM, NPIX, CDIM, 0L, NC, NC, 0L);

    // attention: quarters -> oT, hT (dead), d_out lo/hi; sums -> lbuf
    attn_kernel<<<dim3(512), dim3(512), 0, stream>>>(qT, kT, vv, oT, hT, pq2, pq3, lbuf);

    // combine quarters into qT (dead after attn)
    combine_kernel<<<dim3(2048), dim3(256), 0, stream>>>(oT, hT, pq2, pq3, lbuf, qT);

    gemm_bt_kernel<2><<<dim3(32, 4, 2), dim3(256), 0, stream>>>(
        wob, qT, (void*)out, bo, x, CDIM, NPIX, CDIM, 0L, NC, NC, NC);
}

// Round 13
// 426.015 us; speedup vs baseline: 1.7007x; 1.7007x over previous
//
#include <hip/hip_runtime.h>
#include <stdint.h>

#define NPIX 4096
#define CDIM 512

typedef _Float16 hv8 __attribute__((ext_vector_type(8)));
typedef float f32x4 __attribute__((ext_vector_type(4)));

__device__ __forceinline__ void lds_direct16(const _Float16* g, _Float16* l) {
    __builtin_amdgcn_global_load_lds(
        (const __attribute__((address_space(1))) void*)g,
        (__attribute__((address_space(3))) void*)l, 16, 0, 0);
}

// ---------------- weight fp32 -> fp16 ----------------
__global__ void cvt_w(const float* __restrict__ s0, const float* __restrict__ s1,
                      const float* __restrict__ s2, const float* __restrict__ s3,
                      _Float16* __restrict__ d0, _Float16* __restrict__ d1,
                      _Float16* __restrict__ d2, _Float16* __restrict__ d3) {
    int i = blockIdx.x * 256 + threadIdx.x;
    d0[i] = (_Float16)s0[i];
    d1[i] = (_Float16)s1[i];
    d2[i] = (_Float16)s2[i];
    d3[i] = (_Float16)s3[i];
}

// ---------------- groupnorm stats: one block per (b,g) ----------------
__global__ void stats_kernel(const float* __restrict__ x, float* __restrict__ stats) {
    int idx = blockIdx.x;
    const float4* base = (const float4*)(x + (long)idx * 16 * NPIX);
    int tid = threadIdx.x;
    float s = 0.f, sq = 0.f;
    for (int it = 0; it < 64; ++it) {
        float4 f = base[it * 256 + tid];
        s  += f.x + f.y + f.z + f.w;
        sq += f.x * f.x + f.y * f.y + f.z * f.z + f.w * f.w;
    }
    __shared__ float rs[256], rq[256];
    rs[tid] = s; rq[tid] = sq;
    __syncthreads();
    for (int st = 128; st > 0; st >>= 1) {
        if (tid < st) { rs[tid] += rs[tid + st]; rq[tid] += rq[tid + st]; }
        __syncthreads();
    }
    if (tid == 0) {
        float mean = rs[0] * (1.0f / 65536.0f);
        float var  = rq[0] * (1.0f / 65536.0f) - mean * mean;
        stats[idx * 2]     = mean;
        stats[idx * 2 + 1] = rsqrtf(var + 1e-6f);
    }
}

// ---------------- normalize + transpose: hT[b][n][c] = GN(x)[b][c][n] ----------------
__global__ void normT_kernel(const float* __restrict__ x, const float* __restrict__ stats,
                             const float* __restrict__ gamma, const float* __restrict__ beta,
                             _Float16* __restrict__ hT) {
    int b = blockIdx.z, c0 = blockIdx.x * 32, n0 = blockIdx.y * 32;
    int tid = threadIdx.x;
    __shared__ float t[32][33];
    int cl = tid >> 5;
    int nl = tid & 31;
    for (int r = 0; r < 4; ++r)
        t[r * 8 + cl][nl] = x[(long)b * CDIM * NPIX + (long)(c0 + r * 8 + cl) * NPIX + n0 + nl];
    __syncthreads();
    for (int r = 0; r < 4; ++r) {
        int nr = r * 8 + cl;
        int c = c0 + nl;
        float m    = stats[(b * 32 + (c >> 4)) * 2];
        float rstd = stats[(b * 32 + (c >> 4)) * 2 + 1];
        float val = (t[nl][nr] - m) * rstd * gamma[c] + beta[c];
        hT[(long)b * NPIX * CDIM + (long)(n0 + nr) * CDIM + c] = (_Float16)val;
    }
}

// ---------------- bt-form GEMM: D[M][N] = A[M][K] * BT[N][K]^T ----------------
template<int EPI>
__launch_bounds__(256, 2)
__global__ void gemm_bt_kernel(const _Float16* __restrict__ A, const _Float16* __restrict__ BT,
                               void* __restrict__ D, const float* __restrict__ bias,
                               const float* __restrict__ resid,
                               int M, int N, int K,
                               long aBatch, long bBatch, long dBatch, long rBatch) {
    const int b = blockIdx.z;
    A  += (long)b * aBatch;
    BT += (long)b * bBatch;
    const int m0 = blockIdx.y * 128;
    const int n0 = blockIdx.x * 128;
    const int tid = threadIdx.x;
    const int l = tid & 63;
    const int w = tid >> 6;
    const int wm = (w >> 1) * 64;
    const int wn = (w & 1) * 64;
    const int lr = l & 15;
    const int lk = l >> 4;
    __shared__ __align__(16) _Float16 As[128 * 32];
    __shared__ __align__(16) _Float16 Bs[128 * 32];
    f32x4 acc[4][4] = {};
    const int nK = K >> 5;
    for (int kt = 0; kt < nK; ++kt) {
        const int kb = kt * 32;
#pragma unroll
        for (int c = 0; c < 2; ++c) {
            int chunk = c * 256 + tid;
            int row = chunk >> 2;
            int k8 = (chunk & 3) * 8;
            _Float16* ldsA = As + (size_t)(c * 256 + (tid & ~63)) * 8;
            _Float16* ldsB = Bs + (size_t)(c * 256 + (tid & ~63)) * 8;
            lds_direct16(A  + (long)(m0 + row) * K + kb + k8, ldsA);
            lds_direct16(BT + (long)(n0 + row) * K + kb + k8, ldsB);
        }
        __syncthreads();
        hv8 af[4], bfr[4];
#pragma unroll
        for (int mi = 0; mi < 4; ++mi)
            af[mi] = *(const hv8*)(As + (size_t)(wm + mi * 16 + lr) * 32 + lk * 8);
#pragma unroll
        for (int ni = 0; ni < 4; ++ni)
            bfr[ni] = *(const hv8*)(Bs + (size_t)(wn + ni * 16 + lr) * 32 + lk * 8);
#pragma unroll
        for (int mi = 0; mi < 4; ++mi)
#pragma unroll
            for (int ni = 0; ni < 4; ++ni)
                acc[mi][ni] = __builtin_amdgcn_mfma_f32_16x16x32_f16(af[mi], bfr[ni], acc[mi][ni], 0, 0, 0);
        __syncthreads();
    }
#pragma unroll
    for (int mi = 0; mi < 4; ++mi)
#pragma unroll
        for (int ni = 0; ni < 4; ++ni)
#pragma unroll
            for (int r = 0; r < 4; ++r) {
                int row = m0 + wm + mi * 16 + lk * 4 + r;
                int col = n0 + wn + ni * 16 + lr;
                float val = acc[mi][ni][r];
                if (EPI == 0) {
                    ((_Float16*)D)[(long)b * dBatch + (long)row * N + col] = (_Float16)(val + bias[col]);
                } else if (EPI == 1) {
                    ((_Float16*)D)[(long)b * dBatch + (long)row * N + col] = (_Float16)(val + bias[row]);
                } else {
                    long idx = (long)row * N + col;
                    ((float*)D)[(long)b * dBatch + idx] =
                        val + bias[row] + resid[(long)b * rBatch + idx];
                }
            }
}

// ---------------- flash attention v13: M-register-blocked QK ----------------
// i-tile 64, j-tile 64, j-split 2, XCD pinning, one barrier per step, PV
// deferred one step. Wave grid iq(2) x jq(4): each wave holds TWO Q strips
// (af[2][16], 128 VGPR) and computes 32 i-rows per K-fragment read -> K LDS
// read duplication drops 4 -> 2 (the dominant LDS term halves). 32 steps.
// V in registers (vf[4][2]) single-buffered WAR-safe; counted vmcnt(8).
// ps stride 144 B (16 mod 128 -> all 8 bank groups over 8 rows, conflict-free).
__launch_bounds__(512, 2)
__global__ void attn_kernel(const _Float16* __restrict__ qT, const _Float16* __restrict__ kT,
                            const _Float16* __restrict__ v,
                            _Float16* __restrict__ p0, _Float16* __restrict__ p1,
                            float* __restrict__ lbuf) {
    __shared__ __align__(16) _Float16 Ks[2][64 * 512];   // 128 KB, rows 1 KB, XOR (j&7)<<4
    __shared__ __align__(16) char ps[2][64 * 144];       // 18 KB, 144 B rows
    __shared__ float red[8][64];
    __shared__ float redt[64];

    const int g = blockIdx.x;
    const int xcd = g & 7;
    const int comb = xcd >> 1;                       // (batch, jhalf)
    const int itile = ((g >> 3) << 1) | (xcd & 1);   // 0..63
    const int batch = comb >> 1;
    const int jhalf = comb & 1;
    const int i0 = itile * 64;
    const int jbase = jhalf * 2048;

    const int tid = threadIdx.x;
    const int l = tid & 63, w = tid >> 6;
    const int lr = l & 15, lk = l >> 4;
    const int iq = w >> 2, jq = w & 3;               // QK: rows iq*32 (2 strips), cols jq*16

    const _Float16* qb = qT + (long)batch * NPIX * CDIM;
    const _Float16* kb = kT + (long)batch * NPIX * CDIM;
    const _Float16* vb = v  + (long)batch * CDIM * NPIX;

    // Q fragments: TWO strips of 16 rows (iq*32 + s*16 + lr), 16 k-chunks each
    hv8 af[2][16];
#pragma unroll
    for (int s = 0; s < 2; ++s) {
        const _Float16* qr = qb + (long)(i0 + iq * 32 + s * 16 + lr) * CDIM + lk * 8;
#pragma unroll
        for (int kk = 0; kk < 16; ++kk)
            af[s][kk] = *(const hv8*)(qr + kk * 32);
    }

    f32x4 oacc[4][4] = {};   // rows mi*16+lk*4+r, cols w*64+ni*16+lr (AGPR)
    float lsum[2][4] = {};
    hv8 vf[4][2];            // V(t): wave-unique c-range w*64, j 64 (32 VGPR)

    const _Float16* vptr = vb + (long)(w * 64 + lr) * NPIX + jbase + lk * 8;
    const float scale = 0.044194173824159216f;   // 1/sqrt(512)

// stage K tile JT (64 rows) into Ks[BUF]; 8 instrs/thread, source col pre-swizzled
#define STAGE(BUF, JT)                                                               \
    {                                                                                \
        const long j0s = (long)jbase + (JT) * 64;                                    \
        _Float16* kd = Ks[BUF];                                                      \
        _Pragma("unroll")                                                            \
        for (int q = 0; q < 8; ++q) {                                                \
            int row = q * 8 + w;                                                     \
            int cc = l ^ (row & 7);                                                  \
            lds_direct16(kb + (j0s + row) * CDIM + cc * 8, kd + row * 512);          \
        }                                                                            \
    }

// load V fragments for tile JT (8 x b128 from L2; wave-unique c-range, j 64)
#define VLOAD(JT)                                                                    \
    {                                                                                \
        _Pragma("unroll")                                                            \
        for (int ni = 0; ni < 4; ++ni)                                               \
            _Pragma("unroll")                                                        \
            for (int jh = 0; jh < 2; ++jh)                                           \
                vf[ni][jh] = *(const hv8*)(vptr + (long)ni * (16 * NPIX) + (JT) * 64 + jh * 32); \
    }

// QK(JT) -> exp -> ps[CUR]; one b-frag read feeds BOTH strips (dup 2)
#define QKEXP(CUR)                                                                   \
    {                                                                                \
        const char* kbase = (const char*)Ks[CUR];                                    \
        f32x4 s0 = {}, s1 = {};                                                      \
        const int jj = jq * 16 + lr;                                                 \
        const uint32_t sw = (uint32_t)((jj & 7) << 4);                               \
        _Pragma("unroll")                                                            \
        for (int kk = 0; kk < 16; ++kk) {                                            \
            hv8 bf = *(const hv8*)(kbase + (((uint32_t)(jj * 1024 + kk * 64 + lk * 16)) ^ sw)); \
            s0 = __builtin_amdgcn_mfma_f32_16x16x32_f16(af[0][kk], bf, s0, 0, 0, 0); \
            s1 = __builtin_amdgcn_mfma_f32_16x16x32_f16(af[1][kk], bf, s1, 0, 0, 0); \
        }                                                                            \
        _Pragma("unroll")                                                            \
        for (int r = 0; r < 4; ++r) {                                                \
            float pe0 = __expf(s0[r] * scale);                                       \
            float pe1 = __expf(s1[r] * scale);                                       \
            lsum[0][r] += pe0;                                                       \
            lsum[1][r] += pe1;                                                       \
            int ia = iq * 32 + lk * 4 + r;                                           \
            int j2 = jq * 16 + lr;                                                   \
            *(_Float16*)(ps[CUR] + ia * 144 + j2 * 2) = (_Float16)pe0;               \
            *(_Float16*)(ps[CUR] + (ia + 16) * 144 + j2 * 2) = (_Float16)pe1;        \
        }                                                                            \
    }

// PV of the PREVIOUS step: ps[PRV] (64 rows x 64 j) x vf (holding V(t-1))
#define PVSTEP(PRV)                                                                  \
    {                                                                                \
        _Pragma("unroll")                                                            \
        for (int mi = 0; mi < 4; ++mi) {                                             \
            int row = mi * 16 + lr;                                                  \
            _Pragma("unroll")                                                        \
            for (int jh = 0; jh < 2; ++jh) {                                         \
                hv8 pa = *(const hv8*)(ps[PRV] + row * 144 + jh * 64 + lk * 16);     \
                _Pragma("unroll")                                                    \
                for (int ni = 0; ni < 4; ++ni)                                       \
                    oacc[mi][ni] = __builtin_amdgcn_mfma_f32_16x16x32_f16(pa, vf[ni][jh], oacc[mi][ni], 0, 0, 0); \
            }                                                                        \
        }                                                                            \
    }

// counted end barrier: retires the 8 K-stage loads, keeps the 8 V loads in flight
#define ENDBAR(N)                                                                    \
    __builtin_amdgcn_sched_barrier(0);                                               \
    asm volatile("s_waitcnt vmcnt(" #N ") lgkmcnt(0)" ::: "memory");                 \
    __builtin_amdgcn_s_barrier();                                                    \
    __builtin_amdgcn_sched_barrier(0);

// CUR = compile-time parity of JT (literal). Order: STAGE -> QK -> PV(t-1)
// -> VLOAD(t): vf's load->use window spans QK(t)+barrier+STAGE+QK(t+1).
#define STEP(JT, CUR)                                                                \
    {                                                                                \
        if ((JT) < 31) STAGE((CUR) ^ 1, (JT) + 1)                                    \
        __builtin_amdgcn_sched_barrier(0);                                           \
        __builtin_amdgcn_s_setprio(1);                                               \
        QKEXP(CUR)                                                                   \
        PVSTEP((CUR) ^ 1)                                                            \
        __builtin_amdgcn_s_setprio(0);                                               \
        __builtin_amdgcn_sched_barrier(0);                                           \
        VLOAD(JT)                                                                    \
        ENDBAR(8)                                                                    \
    }

    // prologue: K(0) staged and drained
    STAGE(0, 0)
    __builtin_amdgcn_sched_barrier(0);
    asm volatile("s_waitcnt vmcnt(0)" ::: "memory");
    __builtin_amdgcn_s_barrier();
    __builtin_amdgcn_sched_barrier(0);

    // step 0: no PV yet; V(0) loaded after QK
    STAGE(1, 1)
    __builtin_amdgcn_s_setprio(1);
    QKEXP(0)
    __builtin_amdgcn_s_setprio(0);
    VLOAD(0)
    ENDBAR(8)

    // steady: steps 1..30 in pairs, then 31
    for (int jt = 1; jt < 31; jt += 2) {
        STEP(jt,     1)
        STEP(jt + 1, 0)
    }
    STEP(31, 1)

    // epilogue: PV(31) -- drain the last V loads first
    asm volatile("s_waitcnt vmcnt(0)" ::: "memory");
    __builtin_amdgcn_sched_barrier(0);
    PVSTEP(1)

    // ---- row-sum reduce: over lr (16 lanes), then over the 4 jq waves ----
#pragma unroll
    for (int m = 1; m <= 8; m <<= 1)
#pragma unroll
        for (int s = 0; s < 2; ++s)
#pragma unroll
            for (int r = 0; r < 4; ++r)
                lsum[s][r] += __shfl_xor(lsum[s][r], m, 64);
    if (lr == 0)
#pragma unroll
        for (int s = 0; s < 2; ++s)
#pragma unroll
            for (int r = 0; r < 4; ++r)
                red[w][iq * 32 + s * 16 + lk * 4 + r] = lsum[s][r];
    __syncthreads();
    if (tid < 64) {
        int iq2 = tid >> 5;
        float lv = red[iq2 * 4 + 0][tid] + red[iq2 * 4 + 1][tid]
                 + red[iq2 * 4 + 2][tid] + red[iq2 * 4 + 3][tid];
        redt[tid] = 1.0f / lv;
        lbuf[jhalf * 8192 + batch * NPIX + i0 + tid] = lv;
    }
    __syncthreads();

    // ---- store normalized per-half partial O (fp16) ----
    _Float16* dsth = (jhalf ? p1 : p0) + (long)batch * NPIX * CDIM;
#pragma unroll
    for (int mi = 0; mi < 4; ++mi)
#pragma unroll
        for (int r = 0; r < 4; ++r) {
            int row = mi * 16 + lk * 4 + r;
            float rv = redt[row];
#pragma unroll
            for (int ni = 0; ni < 4; ++ni) {
                int c = w * 64 + ni * 16 + lr;
                dsth[(long)(i0 + row) * CDIM + c] = (_Float16)(oacc[mi][ni][r] * rv);
            }
        }
#undef STEP
#undef ENDBAR
#undef PVSTEP
#undef QKEXP
#undef VLOAD
#undef STAGE
}

// ---------------- combine: out = (O0*l0 + O1*l1) / (l0+l1) ----------------
__global__ void combine_kernel(const _Float16* __restrict__ p0, const _Float16* __restrict__ p1,
                               const float* __restrict__ lbuf, _Float16* __restrict__ out) {
    long g = (long)blockIdx.x * 256 + threadIdx.x;
    long base = g * 8;
    int rowg = (int)(g >> 6);                 // b*4096 + n
    float l0 = lbuf[rowg], l1 = lbuf[8192 + rowg];
    float w0 = l0 / (l0 + l1);
    float w1 = 1.0f - w0;
    hv8 a = *(const hv8*)(p0 + base);
    hv8 b = *(const hv8*)(p1 + base);
    hv8 o;
#pragma unroll
    for (int i = 0; i < 8; ++i)
        o[i] = (_Float16)((float)a[i] * w0 + (float)b[i] * w1);
    *(hv8*)(out + base) = o;
}

extern "C" void kernel_launch(void* const* d_in, const int* in_sizes, int n_in,
                              void* d_out, int out_size, void* d_ws, size_t ws_size,
                              hipStream_t stream) {
    const float* x     = (const float*)d_in[0];
    const float* gamma = (const float*)d_in[1];
    const float* beta  = (const float*)d_in[2];
    const float* wq    = (const float*)d_in[3];
    const float* bq    = (const float*)d_in[4];
    const float* wk    = (const float*)d_in[5];
    const float* bk    = (const float*)d_in[6];
    const float* wv    = (const float*)d_in[7];
    const float* bv    = (const float*)d_in[8];
    const float* wo    = (const float*)d_in[9];
    const float* bo    = (const float*)d_in[10];
    float* out = (float*)d_out;

    char* ws = (char*)d_ws;
    float* stats = (float*)ws;
    _Float16* wqb = (_Float16*)(ws + 1024);
    _Float16* wkb = wqb + 262144;
    _Float16* wvb = wkb + 262144;
    _Float16* wob = wvb + 262144;
    _Float16* hT  = wob + 262144;
    const long TSZ = (long)2 * NPIX * CDIM;
    _Float16* qT = hT + TSZ;
    _Float16* kT = qT + TSZ;
    _Float16* vv = kT + TSZ;
    _Float16* oT = vv + TSZ;
    float* lbuf = (float*)(oT + TSZ);        // 2 halves x 8192 rows

    cvt_w<<<dim3(1024), dim3(256), 0, stream>>>(wq, wk, wv, wo, wqb, wkb, wvb, wob);
    stats_kernel<<<dim3(64), dim3(256), 0, stream>>>(x, stats);
    normT_kernel<<<dim3(16, 128, 2), dim3(256), 0, stream>>>(x, stats, gamma, beta, hT);

    const long NC = (long)NPIX * CDIM;
    gemm_bt_kernel<0><<<dim3(4, 32, 2), dim3(256), 0, stream>>>(
        hT, wqb, (void*)qT, bq, nullptr, NPIX, CDIM, CDIM, NC, 0L, NC, 0L);
    gemm_bt_kernel<0><<<dim3(4, 32, 2), dim3(256), 0, stream>>>(
        hT, wkb, (void*)kT, bk, nullptr, NPIX, CDIM, CDIM, NC, 0L, NC, 0L);
    gemm_bt_kernel<1><<<dim3(32, 4, 2), dim3(256), 0, stream>>>(
        wvb, hT, (void*)vv, bv, nullptr, CDIM, NPIX, CDIM, 0L, NC, NC, 0L);

    // attention: partial jhalf0 -> oT, jhalf1 -> hT (dead), sums -> lbuf
    attn_kernel<<<dim3(256), dim3(512), 0, stream>>>(qT, kT, vv, oT, hT, lbuf);

    // combine halves into qT (dead after attn)
    combine_kernel<<<dim3(2048), dim3(256), 0, stream>>>(oT, hT, lbuf, qT);

    gemm_bt_kernel<2><<<dim3(32, 4, 2), dim3(256), 0, stream>>>(
        wob, qT, (void*)out, bo, x, CDIM, NPIX, CDIM, 0L, NC, NC, NC);
}

// Round 14
// 337.508 us; speedup vs baseline: 2.1467x; 1.2622x over previous
//
#include <hip/hip_runtime.h>
#include <stdint.h>

#define NPIX 4096
#define CDIM 512

typedef _Float16 hv8 __attribute__((ext_vector_type(8)));
typedef float f32x4 __attribute__((ext_vector_type(4)));

__device__ __forceinline__ void lds_direct16(const _Float16* g, _Float16* l) {
    __builtin_amdgcn_global_load_lds(
        (const __attribute__((address_space(1))) void*)g,
        (__attribute__((address_space(3))) void*)l, 16, 0, 0);
}

// ---------------- weight fp32 -> fp16 ----------------
__global__ void cvt_w(const float* __restrict__ s0, const float* __restrict__ s1,
                      const float* __restrict__ s2, const float* __restrict__ s3,
                      _Float16* __restrict__ d0, _Float16* __restrict__ d1,
                      _Float16* __restrict__ d2, _Float16* __restrict__ d3) {
    int i = blockIdx.x * 256 + threadIdx.x;
    d0[i] = (_Float16)s0[i];
    d1[i] = (_Float16)s1[i];
    d2[i] = (_Float16)s2[i];
    d3[i] = (_Float16)s3[i];
}

// ---------------- groupnorm stats: one block per (b,g) ----------------
__global__ void stats_kernel(const float* __restrict__ x, float* __restrict__ stats) {
    int idx = blockIdx.x;
    const float4* base = (const float4*)(x + (long)idx * 16 * NPIX);
    int tid = threadIdx.x;
    float s = 0.f, sq = 0.f;
    for (int it = 0; it < 64; ++it) {
        float4 f = base[it * 256 + tid];
        s  += f.x + f.y + f.z + f.w;
        sq += f.x * f.x + f.y * f.y + f.z * f.z + f.w * f.w;
    }
    __shared__ float rs[256], rq[256];
    rs[tid] = s; rq[tid] = sq;
    __syncthreads();
    for (int st = 128; st > 0; st >>= 1) {
        if (tid < st) { rs[tid] += rs[tid + st]; rq[tid] += rq[tid + st]; }
        __syncthreads();
    }
    if (tid == 0) {
        float mean = rs[0] * (1.0f / 65536.0f);
        float var  = rq[0] * (1.0f / 65536.0f) - mean * mean;
        stats[idx * 2]     = mean;
        stats[idx * 2 + 1] = rsqrtf(var + 1e-6f);
    }
}

// ---------------- normalize + transpose: hT[b][n][c] = GN(x)[b][c][n] ----------------
__global__ void normT_kernel(const float* __restrict__ x, const float* __restrict__ stats,
                             const float* __restrict__ gamma, const float* __restrict__ beta,
                             _Float16* __restrict__ hT) {
    int b = blockIdx.z, c0 = blockIdx.x * 32, n0 = blockIdx.y * 32;
    int tid = threadIdx.x;
    __shared__ float t[32][33];
    int cl = tid >> 5;
    int nl = tid & 31;
    for (int r = 0; r < 4; ++r)
        t[r * 8 + cl][nl] = x[(long)b * CDIM * NPIX + (long)(c0 + r * 8 + cl) * NPIX + n0 + nl];
    __syncthreads();
    for (int r = 0; r < 4; ++r) {
        int nr = r * 8 + cl;
        int c = c0 + nl;
        float m    = stats[(b * 32 + (c >> 4)) * 2];
        float rstd = stats[(b * 32 + (c >> 4)) * 2 + 1];
        float val = (t[nl][nr] - m) * rstd * gamma[c] + beta[c];
        hT[(long)b * NPIX * CDIM + (long)(n0 + nr) * CDIM + c] = (_Float16)val;
    }
}

// ---------------- bt-form GEMM: D[M][N] = A[M][K] * BT[N][K]^T ----------------
template<int EPI>
__launch_bounds__(256, 2)
__global__ void gemm_bt_kernel(const _Float16* __restrict__ A, const _Float16* __restrict__ BT,
                               void* __restrict__ D, const float* __restrict__ bias,
                               const float* __restrict__ resid,
                               int M, int N, int K,
                               long aBatch, long bBatch, long dBatch, long rBatch) {
    const int b = blockIdx.z;
    A  += (long)b * aBatch;
    BT += (long)b * bBatch;
    const int m0 = blockIdx.y * 128;
    const int n0 = blockIdx.x * 128;
    const int tid = threadIdx.x;
    const int l = tid & 63;
    const int w = tid >> 6;
    const int wm = (w >> 1) * 64;
    const int wn = (w & 1) * 64;
    const int lr = l & 15;
    const int lk = l >> 4;
    __shared__ __align__(16) _Float16 As[128 * 32];
    __shared__ __align__(16) _Float16 Bs[128 * 32];
    f32x4 acc[4][4] = {};
    const int nK = K >> 5;
    for (int kt = 0; kt < nK; ++kt) {
        const int kb = kt * 32;
#pragma unroll
        for (int c = 0; c < 2; ++c) {
            int chunk = c * 256 + tid;
            int row = chunk >> 2;
            int k8 = (chunk & 3) * 8;
            _Float16* ldsA = As + (size_t)(c * 256 + (tid & ~63)) * 8;
            _Float16* ldsB = Bs + (size_t)(c * 256 + (tid & ~63)) * 8;
            lds_direct16(A  + (long)(m0 + row) * K + kb + k8, ldsA);
            lds_direct16(BT + (long)(n0 + row) * K + kb + k8, ldsB);
        }
        __syncthreads();
        hv8 af[4], bfr[4];
#pragma unroll
        for (int mi = 0; mi < 4; ++mi)
            af[mi] = *(const hv8*)(As + (size_t)(wm + mi * 16 + lr) * 32 + lk * 8);
#pragma unroll
        for (int ni = 0; ni < 4; ++ni)
            bfr[ni] = *(const hv8*)(Bs + (size_t)(wn + ni * 16 + lr) * 32 + lk * 8);
#pragma unroll
        for (int mi = 0; mi < 4; ++mi)
#pragma unroll
            for (int ni = 0; ni < 4; ++ni)
                acc[mi][ni] = __builtin_amdgcn_mfma_f32_16x16x32_f16(af[mi], bfr[ni], acc[mi][ni], 0, 0, 0);
        __syncthreads();
    }
#pragma unroll
    for (int mi = 0; mi < 4; ++mi)
#pragma unroll
        for (int ni = 0; ni < 4; ++ni)
#pragma unroll
            for (int r = 0; r < 4; ++r) {
                int row = m0 + wm + mi * 16 + lk * 4 + r;
                int col = n0 + wn + ni * 16 + lr;
                float val = acc[mi][ni][r];
                if (EPI == 0) {
                    ((_Float16*)D)[(long)b * dBatch + (long)row * N + col] = (_Float16)(val + bias[col]);
                } else if (EPI == 1) {
                    ((_Float16*)D)[(long)b * dBatch + (long)row * N + col] = (_Float16)(val + bias[row]);
                } else {
                    long idx = (long)row * N + col;
                    ((float*)D)[(long)b * dBatch + idx] =
                        val + bias[row] + resid[(long)b * rBatch + idx];
                }
            }
}

// ---------------- flash attention v14: two barrier domains per CU ----------------
// v11 pipeline (one barrier/step, PV deferred one step, parity-disjoint ps,
// K LDS dbuf via global_load_lds, V regs single-buffered WAR-safe, counted
// vmcnt) reshaped to 256-thread blocks: i-tile 32, 4 waves (iq2 x jq2 QK;
// PV c-split 4 x 128 cols), grid 512 = 2 co-resident blocks/CU. Same per-wave
// register footprint as v11 (af 64 + vf 32 + oacc 64acc) -> no spill; two
// INDEPENDENT barrier domains per CU hide each other's convoy drains.
__launch_bounds__(256, 2)
__global__ void attn_kernel(const _Float16* __restrict__ qT, const _Float16* __restrict__ kT,
                            const _Float16* __restrict__ v,
                            _Float16* __restrict__ p0, _Float16* __restrict__ p1,
                            float* __restrict__ lbuf) {
    __shared__ __align__(16) _Float16 Ks[2][32 * 512];   // 64 KB, rows 1 KB, XOR (j&7)<<4
    __shared__ __align__(16) char ps[2][32 * 80];        // 5 KB, 80 B rows
    __shared__ float red[4][32];
    __shared__ float redt[32];

    const int g = blockIdx.x;                        // 0..511
    const int xcd = g & 7;
    const int comb = xcd >> 1;                       // (batch, jhalf)
    const int itile = ((g >> 3) << 1) | (xcd & 1);   // 0..127
    const int batch = comb >> 1;
    const int jhalf = comb & 1;
    const int i0 = itile * 32;
    const int jbase = jhalf * 2048;

    const int tid = threadIdx.x;
    const int l = tid & 63, w = tid >> 6;            // 4 waves
    const int lr = l & 15, lk = l >> 4;
    const int iq = w >> 1, jq = w & 1;               // QK: rows iq*16, cols jq*16

    const _Float16* qb = qT + (long)batch * NPIX * CDIM;
    const _Float16* kb = kT + (long)batch * NPIX * CDIM;
    const _Float16* vb = v  + (long)batch * CDIM * NPIX;

    // Q fragments: rows i0 + iq*16 + lr, all 16 k-chunks (64 VGPR)
    hv8 af[16];
    {
        const _Float16* qr = qb + (long)(i0 + iq * 16 + lr) * CDIM + lk * 8;
#pragma unroll
        for (int kk = 0; kk < 16; ++kk)
            af[kk] = *(const hv8*)(qr + kk * 32);
    }

    f32x4 oacc[2][8] = {};   // rows mi*16+lk*4+r (32), cols w*128+ni*16+lr (AGPR 64)
    float lsum[4] = {};
    hv8 vf[8];               // V(t): wave-unique c-range w*128, 32 VGPR

    const _Float16* vptr = vb + (long)(w * 128 + lr) * NPIX + jbase + lk * 8;
    const float scale = 0.044194173824159216f;   // 1/sqrt(512)

// stage K tile JT (32 rows) into Ks[BUF]; 8 instrs/thread, source col pre-swizzled
#define STAGE(BUF, JT)                                                               \
    {                                                                                \
        const long j0s = (long)jbase + (JT) * 32;                                    \
        _Float16* kd = Ks[BUF];                                                      \
        _Pragma("unroll")                                                            \
        for (int q = 0; q < 8; ++q) {                                                \
            int row = q * 4 + w;                                                     \
            int cc = l ^ (row & 7);                                                  \
            lds_direct16(kb + (j0s + row) * CDIM + cc * 8, kd + row * 512);          \
        }                                                                            \
    }

// load V fragments for tile JT (8 x b128 from L2; wave-unique 128-col c-range)
#define VLOAD(JT)                                                                    \
    {                                                                                \
        _Pragma("unroll")                                                            \
        for (int ni = 0; ni < 8; ++ni)                                               \
            vf[ni] = *(const hv8*)(vptr + (long)ni * (16 * NPIX) + (JT) * 32);       \
    }

// QK(JT) -> exp -> ps[CUR]
#define QKEXP(CUR)                                                                   \
    {                                                                                \
        const char* kbase = (const char*)Ks[CUR];                                    \
        f32x4 sa = {}, sb = {};                                                      \
        const int jj = jq * 16 + lr;                                                 \
        const uint32_t sw = (uint32_t)((jj & 7) << 4);                               \
        _Pragma("unroll")                                                            \
        for (int kk = 0; kk < 8; ++kk) {                                             \
            hv8 b0 = *(const hv8*)(kbase + (((uint32_t)(jj * 1024 + (2 * kk) * 64 + lk * 16)) ^ sw));     \
            sa = __builtin_amdgcn_mfma_f32_16x16x32_f16(af[2 * kk], b0, sa, 0, 0, 0);                     \
            hv8 b1 = *(const hv8*)(kbase + (((uint32_t)(jj * 1024 + (2 * kk + 1) * 64 + lk * 16)) ^ sw)); \
            sb = __builtin_amdgcn_mfma_f32_16x16x32_f16(af[2 * kk + 1], b1, sb, 0, 0, 0);                 \
        }                                                                            \
        sa += sb;                                                                    \
        _Pragma("unroll")                                                            \
        for (int r = 0; r < 4; ++r) {                                                \
            float p = __expf(sa[r] * scale);                                         \
            lsum[r] += p;                                                            \
            int i = iq * 16 + lk * 4 + r;                                            \
            int j2 = jq * 16 + lr;                                                   \
            *(_Float16*)(ps[CUR] + i * 80 + j2 * 2) = (_Float16)p;                   \
        }                                                                            \
    }

// PV of the PREVIOUS step: ps[PRV] (32 rows) x vf (holding V(t-1))
#define PVSTEP(PRV)                                                                  \
    {                                                                                \
        _Pragma("unroll")                                                            \
        for (int mi = 0; mi < 2; ++mi) {                                             \
            int i2 = mi * 16 + lr;                                                   \
            hv8 pa = *(const hv8*)(ps[PRV] + i2 * 80 + lk * 16);                     \
            _Pragma("unroll")                                                        \
            for (int ni = 0; ni < 8; ++ni)                                           \
                oacc[mi][ni] = __builtin_amdgcn_mfma_f32_16x16x32_f16(pa, vf[ni], oacc[mi][ni], 0, 0, 0); \
        }                                                                            \
    }

// counted end barrier: retires the 8 K-stage loads, keeps the 8 V loads in flight
#define ENDBAR(N)                                                                    \
    __builtin_amdgcn_sched_barrier(0);                                               \
    asm volatile("s_waitcnt vmcnt(" #N ") lgkmcnt(0)" ::: "memory");                 \
    __builtin_amdgcn_s_barrier();                                                    \
    __builtin_amdgcn_sched_barrier(0);

// CUR = compile-time parity of JT (passed as literal).
#define STEP(JT, CUR)                                                                \
    {                                                                                \
        if ((JT) < 63) STAGE((CUR) ^ 1, (JT) + 1)                                    \
        __builtin_amdgcn_sched_barrier(0);                                           \
        __builtin_amdgcn_s_setprio(1);                                               \
        QKEXP(CUR)                                                                   \
        PVSTEP((CUR) ^ 1)                                                            \
        __builtin_amdgcn_s_setprio(0);                                               \
        __builtin_amdgcn_sched_barrier(0);                                           \
        VLOAD(JT)                                                                    \
        ENDBAR(8)                                                                    \
    }

    // prologue: K(0) staged and drained
    STAGE(0, 0)
    __builtin_amdgcn_sched_barrier(0);
    asm volatile("s_waitcnt vmcnt(0)" ::: "memory");
    __builtin_amdgcn_s_barrier();
    __builtin_amdgcn_sched_barrier(0);

    // step 0: no PV yet; V(0) loaded after QK
    STAGE(1, 1)
    __builtin_amdgcn_s_setprio(1);
    QKEXP(0)
    __builtin_amdgcn_s_setprio(0);
    VLOAD(0)
    ENDBAR(8)

    // steady: steps 1..62 in pairs, then 63
    for (int jt = 1; jt < 63; jt += 2) {
        STEP(jt,     1)
        STEP(jt + 1, 0)
    }
    STEP(63, 1)

    // epilogue: PV(63) -- drain the last V loads first
    asm volatile("s_waitcnt vmcnt(0)" ::: "memory");
    __builtin_amdgcn_sched_barrier(0);
    PVSTEP(1)

    // ---- row-sum reduce: over lr (16 lanes), then over the jq wave-pair ----
#pragma unroll
    for (int m = 1; m <= 8; m <<= 1)
#pragma unroll
        for (int r = 0; r < 4; ++r)
            lsum[r] += __shfl_xor(lsum[r], m, 64);
    if (lr == 0)
#pragma unroll
        for (int r = 0; r < 4; ++r)
            red[w][iq * 16 + lk * 4 + r] = lsum[r];
    __syncthreads();
    if (tid < 32) {
        int rw = (tid >> 4) << 1;
        float lv = red[rw][tid] + red[rw + 1][tid];
        redt[tid] = 1.0f / lv;
        lbuf[jhalf * 8192 + batch * NPIX + i0 + tid] = lv;
    }
    __syncthreads();

    // ---- store normalized per-half partial O (fp16) ----
    _Float16* dsth = (jhalf ? p1 : p0) + (long)batch * NPIX * CDIM;
#pragma unroll
    for (int mi = 0; mi < 2; ++mi)
#pragma unroll
        for (int r = 0; r < 4; ++r) {
            int row = mi * 16 + lk * 4 + r;
            float rv = redt[row];
#pragma unroll
            for (int ni = 0; ni < 8; ++ni) {
                int c = w * 128 + ni * 16 + lr;
                dsth[(long)(i0 + row) * CDIM + c] = (_Float16)(oacc[mi][ni][r] * rv);
            }
        }
#undef STEP
#undef ENDBAR
#undef PVSTEP
#undef QKEXP
#undef VLOAD
#undef STAGE
}

// ---------------- combine: out = (O0*l0 + O1*l1) / (l0+l1) ----------------
__global__ void combine_kernel(const _Float16* __restrict__ p0, const _Float16* __restrict__ p1,
                               const float* __restrict__ lbuf, _Float16* __restrict__ out) {
    long g = (long)blockIdx.x * 256 + threadIdx.x;
    long base = g * 8;
    int rowg = (int)(g >> 6);                 // b*4096 + n
    float l0 = lbuf[rowg], l1 = lbuf[8192 + rowg];
    float w0 = l0 / (l0 + l1);
    float w1 = 1.0f - w0;
    hv8 a = *(const hv8*)(p0 + base);
    hv8 b = *(const hv8*)(p1 + base);
    hv8 o;
#pragma unroll
    for (int i = 0; i < 8; ++i)
        o[i] = (_Float16)((float)a[i] * w0 + (float)b[i] * w1);
    *(hv8*)(out + base) = o;
}

extern "C" void kernel_launch(void* const* d_in, const int* in_sizes, int n_in,
                              void* d_out, int out_size, void* d_ws, size_t ws_size,
                              hipStream_t stream) {
    const float* x     = (const float*)d_in[0];
    const float* gamma = (const float*)d_in[1];
    const float* beta  = (const float*)d_in[2];
    const float* wq    = (const float*)d_in[3];
    const float* bq    = (const float*)d_in[4];
    const float* wk    = (const float*)d_in[5];
    const float* bk    = (const float*)d_in[6];
    const float* wv    = (const float*)d_in[7];
    const float* bv    = (const float*)d_in[8];
    const float* wo    = (const float*)d_in[9];
    const float* bo    = (const float*)d_in[10];
    float* out = (float*)d_out;

    char* ws = (char*)d_ws;
    float* stats = (float*)ws;
    _Float16* wqb = (_Float16*)(ws + 1024);
    _Float16* wkb = wqb + 262144;
    _Float16* wvb = wkb + 262144;
    _Float16* wob = wvb + 262144;
    _Float16* hT  = wob + 262144;
    const long TSZ = (long)2 * NPIX * CDIM;
    _Float16* qT = hT + TSZ;
    _Float16* kT = qT + TSZ;
    _Float16* vv = kT + TSZ;
    _Float16* oT = vv + TSZ;
    float* lbuf = (float*)(oT + TSZ);        // 2 halves x 8192 rows

    cvt_w<<<dim3(1024), dim3(256), 0, stream>>>(wq, wk, wv, wo, wqb, wkb, wvb, wob);
    stats_kernel<<<dim3(64), dim3(256), 0, stream>>>(x, stats);
    normT_kernel<<<dim3(16, 128, 2), dim3(256), 0, stream>>>(x, stats, gamma, beta, hT);

    const long NC = (long)NPIX * CDIM;
    gemm_bt_kernel<0><<<dim3(4, 32, 2), dim3(256), 0, stream>>>(
        hT, wqb, (void*)qT, bq, nullptr, NPIX, CDIM, CDIM, NC, 0L, NC, 0L);
    gemm_bt_kernel<0><<<dim3(4, 32, 2), dim3(256), 0, stream>>>(
        hT, wkb, (void*)kT, bk, nullptr, NPIX, CDIM, CDIM, NC, 0L, NC, 0L);
    gemm_bt_kernel<1><<<dim3(32, 4, 2), dim3(256), 0, stream>>>(
        wvb, hT, (void*)vv, bv, nullptr, CDIM, NPIX, CDIM, 0L, NC, NC, 0L);

    // attention: partial jhalf0 -> oT, jhalf1 -> hT (dead), sums -> lbuf
    attn_kernel<<<dim3(512), dim3(256), 0, stream>>>(qT, kT, vv, oT, hT, lbuf);

    // combine halves into qT (dead after attn)
    combine_kernel<<<dim3(2048), dim3(256), 0, stream>>>(oT, hT, lbuf, qT);

    gemm_bt_kernel<2><<<dim3(32, 4, 2), dim3(256), 0, stream>>>(
        wob, qT, (void*)out, bo, x, CDIM, NPIX, CDIM, 0L, NC, NC, NC);
}

// Round 15
// 181.530 us; speedup vs baseline: 3.9912x; 1.8592x over previous
//
#include <hip/hip_runtime.h>
#include <stdint.h>

#define NPIX 4096
#define CDIM 512

typedef _Float16 hv8 __attribute__((ext_vector_type(8)));
typedef float f32x4 __attribute__((ext_vector_type(4)));

__device__ __forceinline__ void lds_direct16(const _Float16* g, _Float16* l) {
    __builtin_amdgcn_global_load_lds(
        (const __attribute__((address_space(1))) void*)g,
        (__attribute__((address_space(3))) void*)l, 16, 0, 0);
}

// ---------------- weight fp32 -> fp16 (+ bias concat bq||bk) ----------------
__global__ void cvt_w(const float* __restrict__ s0, const float* __restrict__ s1,
                      const float* __restrict__ s2, const float* __restrict__ s3,
                      _Float16* __restrict__ d0, _Float16* __restrict__ d1,
                      _Float16* __restrict__ d2, _Float16* __restrict__ d3,
                      const float* __restrict__ bq, const float* __restrict__ bk,
                      float* __restrict__ bqk) {
    int i = blockIdx.x * 256 + threadIdx.x;
    d0[i] = (_Float16)s0[i];
    d1[i] = (_Float16)s1[i];
    d2[i] = (_Float16)s2[i];
    d3[i] = (_Float16)s3[i];
    if (i < 512) { bqk[i] = bq[i]; bqk[i + 512] = bk[i]; }
}

// ---------------- groupnorm partial stats: 8 blocks per (b,g) ----------------
__global__ void pstats_kernel(const float* __restrict__ x,
                              float* __restrict__ partS, float* __restrict__ partQ) {
    int pb = blockIdx.x;                 // 0..511
    int gi = pb >> 3;                    // global group 0..63
    int sl = pb & 7;                     // slice
    const float4* base = (const float4*)x + (long)gi * 16384 + sl * 2048;
    int tid = threadIdx.x;
    float s = 0.f, sq = 0.f;
    for (int it = 0; it < 8; ++it) {
        float4 f = base[it * 256 + tid];
        s  += f.x + f.y + f.z + f.w;
        sq += f.x * f.x + f.y * f.y + f.z * f.z + f.w * f.w;
    }
    __shared__ float rs[256], rq[256];
    rs[tid] = s; rq[tid] = sq;
    __syncthreads();
    for (int st = 128; st > 0; st >>= 1) {
        if (tid < st) { rs[tid] += rs[tid + st]; rq[tid] += rq[tid + st]; }
        __syncthreads();
    }
    if (tid == 0) { partS[pb] = rs[0]; partQ[pb] = rq[0]; }
}

// ---------------- normalize + transpose (stats finalized inline) ----------------
__global__ void normT_kernel(const float* __restrict__ x,
                             const float* __restrict__ partS, const float* __restrict__ partQ,
                             const float* __restrict__ gamma, const float* __restrict__ beta,
                             _Float16* __restrict__ hT) {
    int b = blockIdx.z, c0 = blockIdx.x * 32, n0 = blockIdx.y * 32;
    int tid = threadIdx.x;
    __shared__ float t[32][33];
    int cl = tid >> 5;
    int nl = tid & 31;
    for (int r = 0; r < 4; ++r)
        t[r * 8 + cl][nl] = x[(long)b * CDIM * NPIX + (long)(c0 + r * 8 + cl) * NPIX + n0 + nl];
    __syncthreads();
    int c = c0 + nl;
    int gg = b * 32 + (c >> 4);
    float s = 0.f, q = 0.f;
#pragma unroll
    for (int k2 = 0; k2 < 8; ++k2) { s += partS[gg * 8 + k2]; q += partQ[gg * 8 + k2]; }
    float m    = s * (1.0f / 65536.0f);
    float rstd = rsqrtf(q * (1.0f / 65536.0f) - m * m + 1e-6f);
    float gm = gamma[c], bt = beta[c];
    for (int r = 0; r < 4; ++r) {
        int nr = r * 8 + cl;
        float val = (t[nl][nr] - m) * rstd * gm + bt;
        hT[(long)b * NPIX * CDIM + (long)(n0 + nr) * CDIM + c] = (_Float16)val;
    }
}

// ---------------- bt-form GEMM: D[M][N] = A[M][K] * BT[N][K]^T ----------------
// EPI 0: fp16 store, bias[col]    EPI 1: fp16 store, bias[row]
// EPI 2: fp32 store, bias[row] + residual
// EPI 3: fused q|k -> col<512 to D (qT), col>=512 to D + 2*NPIX*CDIM (kT)
template<int EPI>
__launch_bounds__(256, 2)
__global__ void gemm_bt_kernel(const _Float16* __restrict__ A, const _Float16* __restrict__ BT,
                               void* __restrict__ D, const float* __restrict__ bias,
                               const float* __restrict__ resid,
                               int M, int N, int K,
                               long aBatch, long bBatch, long dBatch, long rBatch) {
    const int b = blockIdx.z;
    A  += (long)b * aBatch;
    BT += (long)b * bBatch;
    const int m0 = blockIdx.y * 128;
    const int n0 = blockIdx.x * 128;
    const int tid = threadIdx.x;
    const int l = tid & 63;
    const int w = tid >> 6;
    const int wm = (w >> 1) * 64;
    const int wn = (w & 1) * 64;
    const int lr = l & 15;
    const int lk = l >> 4;
    __shared__ __align__(16) _Float16 As[128 * 32];
    __shared__ __align__(16) _Float16 Bs[128 * 32];
    f32x4 acc[4][4] = {};
    const int nK = K >> 5;
    for (int kt = 0; kt < nK; ++kt) {
        const int kb = kt * 32;
#pragma unroll
        for (int c = 0; c < 2; ++c) {
            int chunk = c * 256 + tid;
            int row = chunk >> 2;
            int k8 = (chunk & 3) * 8;
            _Float16* ldsA = As + (size_t)(c * 256 + (tid & ~63)) * 8;
            _Float16* ldsB = Bs + (size_t)(c * 256 + (tid & ~63)) * 8;
            lds_direct16(A  + (long)(m0 + row) * K + kb + k8, ldsA);
            lds_direct16(BT + (long)(n0 + row) * K + kb + k8, ldsB);
        }
        __syncthreads();
        hv8 af[4], bfr[4];
#pragma unroll
        for (int mi = 0; mi < 4; ++mi)
            af[mi] = *(const hv8*)(As + (size_t)(wm + mi * 16 + lr) * 32 + lk * 8);
#pragma unroll
        for (int ni = 0; ni < 4; ++ni)
            bfr[ni] = *(const hv8*)(Bs + (size_t)(wn + ni * 16 + lr) * 32 + lk * 8);
#pragma unroll
        for (int mi = 0; mi < 4; ++mi)
#pragma unroll
            for (int ni = 0; ni < 4; ++ni)
                acc[mi][ni] = __builtin_amdgcn_mfma_f32_16x16x32_f16(af[mi], bfr[ni], acc[mi][ni], 0, 0, 0);
        __syncthreads();
    }
#pragma unroll
    for (int mi = 0; mi < 4; ++mi)
#pragma unroll
        for (int ni = 0; ni < 4; ++ni)
#pragma unroll
            for (int r = 0; r < 4; ++r) {
                int row = m0 + wm + mi * 16 + lk * 4 + r;
                int col = n0 + wn + ni * 16 + lr;
                float val = acc[mi][ni][r];
                if (EPI == 0) {
                    ((_Float16*)D)[(long)b * dBatch + (long)row * N + col] = (_Float16)(val + bias[col]);
                } else if (EPI == 1) {
                    ((_Float16*)D)[(long)b * dBatch + (long)row * N + col] = (_Float16)(val + bias[row]);
                } else if (EPI == 2) {
                    long idx = (long)row * N + col;
                    ((float*)D)[(long)b * dBatch + idx] =
                        val + bias[row] + resid[(long)b * rBatch + idx];
                } else {
                    long qoff = (long)(col >> 9) * (2L * NPIX * CDIM);
                    ((_Float16*)D)[qoff + (long)b * dBatch + (long)row * CDIM + (col & 511)] =
                        (_Float16)(val + bias[col]);
                }
            }
}

// ---------------- flash attention v11 (champion, unchanged) ----------------
__launch_bounds__(512, 2)
__global__ void attn_kernel(const _Float16* __restrict__ qT, const _Float16* __restrict__ kT,
                            const _Float16* __restrict__ v,
                            _Float16* __restrict__ p0, _Float16* __restrict__ p1,
                            float* __restrict__ lbuf) {
    __shared__ __align__(16) _Float16 Ks[2][32 * 512];   // 64 KB, rows 1 KB, XOR (j&7)<<4
    __shared__ __align__(16) char ps[2][64 * 80];        // 10 KB, 80 B rows
    __shared__ float red[8][64];
    __shared__ float redt[64];

    const int g = blockIdx.x;
    const int xcd = g & 7;
    const int comb = xcd >> 1;                       // (batch, jhalf)
    const int itile = ((g >> 3) << 1) | (xcd & 1);   // 0..63
    const int batch = comb >> 1;
    const int jhalf = comb & 1;
    const int i0 = itile * 64;
    const int jbase = jhalf * 2048;

    const int tid = threadIdx.x;
    const int l = tid & 63, w = tid >> 6;
    const int lr = l & 15, lk = l >> 4;
    const int iq = w >> 1, jq = w & 1;               // QK: rows iq*16, cols jq*16

    const _Float16* qb = qT + (long)batch * NPIX * CDIM;
    const _Float16* kb = kT + (long)batch * NPIX * CDIM;
    const _Float16* vb = v  + (long)batch * CDIM * NPIX;

    hv8 af[16];
    {
        const _Float16* qr = qb + (long)(i0 + iq * 16 + lr) * CDIM + lk * 8;
#pragma unroll
        for (int kk = 0; kk < 16; ++kk)
            af[kk] = *(const hv8*)(qr + kk * 32);
    }

    f32x4 oacc[4][4] = {};
    float lsum[4] = {};
    hv8 vf[4];

    const _Float16* vptr = vb + (long)(w * 64 + lr) * NPIX + jbase + lk * 8;
    const float scale = 0.044194173824159216f;   // 1/sqrt(512)

#define STAGE(BUF, JT)                                                               \
    {                                                                                \
        const long j0s = (long)jbase + (JT) * 32;                                    \
        _Float16* kd = Ks[BUF];                                                      \
        _Pragma("unroll")                                                            \
        for (int q = 0; q < 4; ++q) {                                                \
            int row = q * 8 + w;                                                     \
            int cc = l ^ (row & 7);                                                  \
            lds_direct16(kb + (j0s + row) * CDIM + cc * 8, kd + row * 512);          \
        }                                                                            \
    }

#define VLOAD(JT)                                                                    \
    {                                                                                \
        _Pragma("unroll")                                                            \
        for (int ni = 0; ni < 4; ++ni)                                               \
            vf[ni] = *(const hv8*)(vptr + (long)ni * (16 * NPIX) + (JT) * 32);       \
    }

#define QKEXP(CUR)                                                                   \
    {                                                                                \
        const char* kbase = (const char*)Ks[CUR];                                    \
        f32x4 sa = {}, sb = {};                                                      \
        const int jj = jq * 16 + lr;                                                 \
        const uint32_t sw = (uint32_t)((jj & 7) << 4);                               \
        _Pragma("unroll")                                                            \
        for (int kk = 0; kk < 8; ++kk) {                                             \
            hv8 b0 = *(const hv8*)(kbase + (((uint32_t)(jj * 1024 + (2 * kk) * 64 + lk * 16)) ^ sw));     \
            sa = __builtin_amdgcn_mfma_f32_16x16x32_f16(af[2 * kk], b0, sa, 0, 0, 0);                     \
            hv8 b1 = *(const hv8*)(kbase + (((uint32_t)(jj * 1024 + (2 * kk + 1) * 64 + lk * 16)) ^ sw)); \
            sb = __builtin_amdgcn_mfma_f32_16x16x32_f16(af[2 * kk + 1], b1, sb, 0, 0, 0);                 \
        }                                                                            \
        sa += sb;                                                                    \
        _Pragma("unroll")                                                            \
        for (int r = 0; r < 4; ++r) {                                                \
            float p = __expf(sa[r] * scale);                                         \
            lsum[r] += p;                                                            \
            int i = iq * 16 + lk * 4 + r;                                            \
            int j2 = jq * 16 + lr;                                                   \
            *(_Float16*)(ps[CUR] + i * 80 + j2 * 2) = (_Float16)p;                   \
        }                                                                            \
    }

#define PVSTEP(PRV)                                                                  \
    {                                                                                \
        _Pragma("unroll")                                                            \
        for (int mi = 0; mi < 4; ++mi) {                                             \
            int i2 = mi * 16 + lr;                                                   \
            hv8 pa = *(const hv8*)(ps[PRV] + i2 * 80 + lk * 16);                     \
            _Pragma("unroll")                                                        \
            for (int ni = 0; ni < 4; ++ni)                                           \
                oacc[mi][ni] = __builtin_amdgcn_mfma_f32_16x16x32_f16(pa, vf[ni], oacc[mi][ni], 0, 0, 0); \
        }                                                                            \
    }

#define ENDBAR(N)                                                                    \
    __builtin_amdgcn_sched_barrier(0);                                               \
    asm volatile("s_waitcnt vmcnt(" #N ") lgkmcnt(0)" ::: "memory");                 \
    __builtin_amdgcn_s_barrier();                                                    \
    __builtin_amdgcn_sched_barrier(0);

#define STEP(JT, CUR)                                                                \
    {                                                                                \
        if ((JT) < 63) STAGE((CUR) ^ 1, (JT) + 1)                                    \
        __builtin_amdgcn_sched_barrier(0);                                           \
        __builtin_amdgcn_s_setprio(1);                                               \
        QKEXP(CUR)                                                                   \
        PVSTEP((CUR) ^ 1)                                                            \
        __builtin_amdgcn_s_setprio(0);                                               \
        __builtin_amdgcn_sched_barrier(0);                                           \
        VLOAD(JT)                                                                    \
        ENDBAR(4)                                                                    \
    }

    STAGE(0, 0)
    __builtin_amdgcn_sched_barrier(0);
    asm volatile("s_waitcnt vmcnt(0)" ::: "memory");
    __builtin_amdgcn_s_barrier();
    __builtin_amdgcn_sched_barrier(0);

    STAGE(1, 1)
    __builtin_amdgcn_s_setprio(1);
    QKEXP(0)
    __builtin_amdgcn_s_setprio(0);
    VLOAD(0)
    ENDBAR(4)

    for (int jt = 1; jt < 63; jt += 2) {
        STEP(jt,     1)
        STEP(jt + 1, 0)
    }
    STEP(63, 1)

    asm volatile("s_waitcnt vmcnt(0)" ::: "memory");
    __builtin_amdgcn_sched_barrier(0);
    PVSTEP(1)

#pragma unroll
    for (int m = 1; m <= 8; m <<= 1)
#pragma unroll
        for (int r = 0; r < 4; ++r)
            lsum[r] += __shfl_xor(lsum[r], m, 64);
    if (lr == 0)
#pragma unroll
        for (int r = 0; r < 4; ++r)
            red[w][iq * 16 + lk * 4 + r] = lsum[r];
    __syncthreads();
    if (tid < 64) {
        int iq2 = tid >> 4;
        float lv = red[iq2 * 2][tid] + red[iq2 * 2 + 1][tid];
        redt[tid] = 1.0f / lv;
        lbuf[jhalf * 8192 + batch * NPIX + i0 + tid] = lv;
    }
    __syncthreads();

    _Float16* dsth = (jhalf ? p1 : p0) + (long)batch * NPIX * CDIM;
#pragma unroll
    for (int mi = 0; mi < 4; ++mi)
#pragma unroll
        for (int r = 0; r < 4; ++r) {
            int row = mi * 16 + lk * 4 + r;
            float rv = redt[row];
#pragma unroll
            for (int ni = 0; ni < 4; ++ni) {
                int c = w * 64 + ni * 16 + lr;
                dsth[(long)(i0 + row) * CDIM + c] = (_Float16)(oacc[mi][ni][r] * rv);
            }
        }
#undef STEP
#undef ENDBAR
#undef PVSTEP
#undef QKEXP
#undef VLOAD
#undef STAGE
}

// ---------------- combine: out = (O0*l0 + O1*l1) / (l0+l1) ----------------
__global__ void combine_kernel(const _Float16* __restrict__ p0, const _Float16* __restrict__ p1,
                               const float* __restrict__ lbuf, _Float16* __restrict__ out) {
    long g = (long)blockIdx.x * 256 + threadIdx.x;
    long base = g * 8;
    int rowg = (int)(g >> 6);                 // b*4096 + n
    float l0 = lbuf[rowg], l1 = lbuf[8192 + rowg];
    float w0 = l0 / (l0 + l1);
    float w1 = 1.0f - w0;
    hv8 a = *(const hv8*)(p0 + base);
    hv8 b = *(const hv8*)(p1 + base);
    hv8 o;
#pragma unroll
    for (int i = 0; i < 8; ++i)
        o[i] = (_Float16)((float)a[i] * w0 + (float)b[i] * w1);
    *(hv8*)(out + base) = o;
}

extern "C" void kernel_launch(void* const* d_in, const int* in_sizes, int n_in,
                              void* d_out, int out_size, void* d_ws, size_t ws_size,
                              hipStream_t stream) {
    const float* x     = (const float*)d_in[0];
    const float* gamma = (const float*)d_in[1];
    const float* beta  = (const float*)d_in[2];
    const float* wq    = (const float*)d_in[3];
    const float* bq    = (const float*)d_in[4];
    const float* wk    = (const float*)d_in[5];
    const float* bk    = (const float*)d_in[6];
    const float* wv    = (const float*)d_in[7];
    const float* bv    = (const float*)d_in[8];
    const float* wo    = (const float*)d_in[9];
    const float* bo    = (const float*)d_in[10];
    float* out = (float*)d_out;

    char* ws = (char*)d_ws;
    float* partS = (float*)ws;               // 512
    float* partQ = partS + 512;              // 512
    float* bqk   = partQ + 512;              // 1024
    _Float16* wqb = (_Float16*)(ws + 8192);  // wq|wk adjacent -> fused BT [1024][512]
    _Float16* wkb = wqb + 262144;
    _Float16* wvb = wkb + 262144;
    _Float16* wob = wvb + 262144;
    _Float16* hT  = wob + 262144;
    const long TSZ = (long)2 * NPIX * CDIM;
    _Float16* qT = hT + TSZ;
    _Float16* kT = qT + TSZ;                 // = qT + 2*NPIX*CDIM (EPI3 relies on this)
    _Float16* vv = kT + TSZ;
    _Float16* oT = vv + TSZ;
    float* lbuf = (float*)(oT + TSZ);        // 2 halves x 8192 rows

    cvt_w<<<dim3(1024), dim3(256), 0, stream>>>(wq, wk, wv, wo, wqb, wkb, wvb, wob,
                                                bq, bk, bqk);
    pstats_kernel<<<dim3(512), dim3(256), 0, stream>>>(x, partS, partQ);
    normT_kernel<<<dim3(16, 128, 2), dim3(256), 0, stream>>>(x, partS, partQ, gamma, beta, hT);

    const long NC = (long)NPIX * CDIM;
    // fused q|k GEMM: M=4096, N=1024 (cols 0..511 -> qT, 512..1023 -> kT)
    gemm_bt_kernel<3><<<dim3(8, 32, 2), dim3(256), 0, stream>>>(
        hT, wqb, (void*)qT, bqk, nullptr, NPIX, 1024, CDIM, NC, 0L, NC, 0L);
    gemm_bt_kernel<1><<<dim3(32, 4, 2), dim3(256), 0, stream>>>(
        wvb, hT, (void*)vv, bv, nullptr, CDIM, NPIX, CDIM, 0L, NC, NC, 0L);

    // attention: partial jhalf0 -> oT, jhalf1 -> hT (dead), sums -> lbuf
    attn_kernel<<<dim3(256), dim3(512), 0, stream>>>(qT, kT, vv, oT, hT, lbuf);

    // combine halves into qT (dead after attn)
    combine_kernel<<<dim3(2048), dim3(256), 0, stream>>>(oT, hT, lbuf, qT);

    gemm_bt_kernel<2><<<dim3(32, 4, 2), dim3(256), 0, stream>>>(
        wob, qT, (void*)out, bo, x, CDIM, NPIX, CDIM, 0L, NC, NC, NC);
}

// Round 16
// 177.767 us; speedup vs baseline: 4.0757x; 1.0212x over previous
//
#include <hip/hip_runtime.h>
#include <stdint.h>

#define NPIX 4096
#define CDIM 512

typedef _Float16 hv8 __attribute__((ext_vector_type(8)));
typedef float f32x4 __attribute__((ext_vector_type(4)));

__device__ __forceinline__ void lds_direct16(const _Float16* g, _Float16* l) {
    __builtin_amdgcn_global_load_lds(
        (const __attribute__((address_space(1))) void*)g,
        (__attribute__((address_space(3))) void*)l, 16, 0, 0);
}

// ---------------- groupnorm partial stats + weight fp32->fp16 conversion ----------------
__global__ void pstats_kernel(const float* __restrict__ x,
                              float* __restrict__ partS, float* __restrict__ partQ,
                              const float* __restrict__ wq, const float* __restrict__ wk,
                              const float* __restrict__ wv, const float* __restrict__ wo,
                              _Float16* __restrict__ d0, _Float16* __restrict__ d1,
                              _Float16* __restrict__ d2, _Float16* __restrict__ d3,
                              const float* __restrict__ bq, const float* __restrict__ bk,
                              float* __restrict__ bqk) {
    int pb = blockIdx.x;                 // 0..511
    int tid = threadIdx.x;

    // fused weight conversion: 2 elements per thread per array
#pragma unroll
    for (int h = 0; h < 2; ++h) {
        int ii = pb * 512 + h * 256 + tid;
        d0[ii] = (_Float16)wq[ii];
        d1[ii] = (_Float16)wk[ii];
        d2[ii] = (_Float16)wv[ii];
        d3[ii] = (_Float16)wo[ii];
        if (ii < 512) bqk[ii] = bq[ii];
        else if (ii < 1024) bqk[ii] = bk[ii - 512];
    }

    // partial stats: 8 blocks per (b,g) group
    int gi = pb >> 3;                    // global group 0..63
    int sl = pb & 7;                     // slice
    const float4* base = (const float4*)x + (long)gi * 16384 + sl * 2048;
    float s = 0.f, sq = 0.f;
    for (int it = 0; it < 8; ++it) {
        float4 f = base[it * 256 + tid];
        s  += f.x + f.y + f.z + f.w;
        sq += f.x * f.x + f.y * f.y + f.z * f.z + f.w * f.w;
    }
    __shared__ float rs[256], rq[256];
    rs[tid] = s; rq[tid] = sq;
    __syncthreads();
    for (int st = 128; st > 0; st >>= 1) {
        if (tid < st) { rs[tid] += rs[tid + st]; rq[tid] += rq[tid + st]; }
        __syncthreads();
    }
    if (tid == 0) { partS[pb] = rs[0]; partQ[pb] = rq[0]; }
}

// ---------------- normalize + transpose (stats finalized inline) ----------------
__global__ void normT_kernel(const float* __restrict__ x,
                             const float* __restrict__ partS, const float* __restrict__ partQ,
                             const float* __restrict__ gamma, const float* __restrict__ beta,
                             _Float16* __restrict__ hT) {
    int b = blockIdx.z, c0 = blockIdx.x * 32, n0 = blockIdx.y * 32;
    int tid = threadIdx.x;
    __shared__ float t[32][33];
    int cl = tid >> 5;
    int nl = tid & 31;
    for (int r = 0; r < 4; ++r)
        t[r * 8 + cl][nl] = x[(long)b * CDIM * NPIX + (long)(c0 + r * 8 + cl) * NPIX + n0 + nl];
    __syncthreads();
    int c = c0 + nl;
    int gg = b * 32 + (c >> 4);
    float s = 0.f, q = 0.f;
#pragma unroll
    for (int k2 = 0; k2 < 8; ++k2) { s += partS[gg * 8 + k2]; q += partQ[gg * 8 + k2]; }
    float m    = s * (1.0f / 65536.0f);
    float rstd = rsqrtf(q * (1.0f / 65536.0f) - m * m + 1e-6f);
    float gm = gamma[c], bt = beta[c];
    for (int r = 0; r < 4; ++r) {
        int nr = r * 8 + cl;
        float val = (t[nl][nr] - m) * rstd * gm + bt;
        hT[(long)b * NPIX * CDIM + (long)(n0 + nr) * CDIM + c] = (_Float16)val;
    }
}

// ---------------- bt-form GEMM: D[M][N] = A[M][K] * BT[N][K]^T ----------------
// EPI 1: fp16 store, bias[row]
// EPI 3: fused q|k -> col<512 to D (qT), col>=512 to D + 2*NPIX*CDIM (kT)
template<int EPI>
__launch_bounds__(256, 2)
__global__ void gemm_bt_kernel(const _Float16* __restrict__ A, const _Float16* __restrict__ BT,
                               void* __restrict__ D, const float* __restrict__ bias,
                               int M, int N, int K,
                               long aBatch, long bBatch, long dBatch) {
    const int b = blockIdx.z;
    A  += (long)b * aBatch;
    BT += (long)b * bBatch;
    const int m0 = blockIdx.y * 128;
    const int n0 = blockIdx.x * 128;
    const int tid = threadIdx.x;
    const int l = tid & 63;
    const int w = tid >> 6;
    const int wm = (w >> 1) * 64;
    const int wn = (w & 1) * 64;
    const int lr = l & 15;
    const int lk = l >> 4;
    __shared__ __align__(16) _Float16 As[128 * 32];
    __shared__ __align__(16) _Float16 Bs[128 * 32];
    f32x4 acc[4][4] = {};
    const int nK = K >> 5;
    for (int kt = 0; kt < nK; ++kt) {
        const int kb = kt * 32;
#pragma unroll
        for (int c = 0; c < 2; ++c) {
            int chunk = c * 256 + tid;
            int row = chunk >> 2;
            int k8 = (chunk & 3) * 8;
            _Float16* ldsA = As + (size_t)(c * 256 + (tid & ~63)) * 8;
            _Float16* ldsB = Bs + (size_t)(c * 256 + (tid & ~63)) * 8;
            lds_direct16(A  + (long)(m0 + row) * K + kb + k8, ldsA);
            lds_direct16(BT + (long)(n0 + row) * K + kb + k8, ldsB);
        }
        __syncthreads();
        hv8 af[4], bfr[4];
#pragma unroll
        for (int mi = 0; mi < 4; ++mi)
            af[mi] = *(const hv8*)(As + (size_t)(wm + mi * 16 + lr) * 32 + lk * 8);
#pragma unroll
        for (int ni = 0; ni < 4; ++ni)
            bfr[ni] = *(const hv8*)(Bs + (size_t)(wn + ni * 16 + lr) * 32 + lk * 8);
#pragma unroll
        for (int mi = 0; mi < 4; ++mi)
#pragma unroll
            for (int ni = 0; ni < 4; ++ni)
                acc[mi][ni] = __builtin_amdgcn_mfma_f32_16x16x32_f16(af[mi], bfr[ni], acc[mi][ni], 0, 0, 0);
        __syncthreads();
    }
#pragma unroll
    for (int mi = 0; mi < 4; ++mi)
#pragma unroll
        for (int ni = 0; ni < 4; ++ni)
#pragma unroll
            for (int r = 0; r < 4; ++r) {
                int row = m0 + wm + mi * 16 + lk * 4 + r;
                int col = n0 + wn + ni * 16 + lr;
                float val = acc[mi][ni][r];
                if (EPI == 1) {
                    ((_Float16*)D)[(long)b * dBatch + (long)row * N + col] = (_Float16)(val + bias[row]);
                } else {
                    long qoff = (long)(col >> 9) * (2L * NPIX * CDIM);
                    ((_Float16*)D)[qoff + (long)b * dBatch + (long)row * CDIM + (col & 511)] =
                        (_Float16)(val + bias[col]);
                }
            }
}

// ---------------- final GEMM with fused combine ----------------
// out[b][row][col] = sum_c wo[row][c] * comb[b][col][c] + bo[row] + x[b][row][col]
// comb[b][n][c] = p0*w0 + p1*w1 with per-row weights from lbuf (fused staging).
__launch_bounds__(256, 2)
__global__ void gemm_final_kernel(const _Float16* __restrict__ A,      // wob [512][512]
                                  const _Float16* __restrict__ p0,     // [B][4096][512]
                                  const _Float16* __restrict__ p1,
                                  const float* __restrict__ lbuf,
                                  float* __restrict__ D, const float* __restrict__ bias,
                                  const float* __restrict__ resid) {
    const int b = blockIdx.z;
    const int m0 = blockIdx.y * 128;
    const int n0 = blockIdx.x * 128;
    const int tid = threadIdx.x;
    const int l = tid & 63;
    const int w = tid >> 6;
    const int wm = (w >> 1) * 64;
    const int wn = (w & 1) * 64;
    const int lr = l & 15;
    const int lk = l >> 4;
    __shared__ __align__(16) _Float16 As[128 * 32];
    __shared__ __align__(16) _Float16 Bs[128 * 32];
    __shared__ float wA[128], wB[128];

    // per-row combine weights
    if (tid < 128) {
        int rowg = b * NPIX + n0 + tid;
        float l0 = lbuf[rowg], l1 = lbuf[8192 + rowg];
        float inv = 1.0f / (l0 + l1);
        wA[tid] = l0 * inv;
        wB[tid] = l1 * inv;
    }
    __syncthreads();

    const _Float16* pb0 = p0 + (long)b * NPIX * CDIM;
    const _Float16* pb1 = p1 + (long)b * NPIX * CDIM;

    f32x4 acc[4][4] = {};
    for (int kt = 0; kt < 16; ++kt) {
        const int kb = kt * 32;
#pragma unroll
        for (int c = 0; c < 2; ++c) {
            int chunk = c * 256 + tid;
            int row = chunk >> 2;
            int k8 = (chunk & 3) * 8;
            // A (weights): async direct-to-LDS
            _Float16* ldsA = As + (size_t)(c * 256 + (tid & ~63)) * 8;
            lds_direct16(A + (long)(m0 + row) * CDIM + kb + k8, ldsA);
            // B (combined O): reg-staged with combine math
            long goff = (long)(n0 + row) * CDIM + kb + k8;
            hv8 va = *(const hv8*)(pb0 + goff);
            hv8 vb = *(const hv8*)(pb1 + goff);
            float w0 = wA[row], w1 = wB[row];
            hv8 vo;
#pragma unroll
            for (int i = 0; i < 8; ++i)
                vo[i] = (_Float16)((float)va[i] * w0 + (float)vb[i] * w1);
            *(hv8*)(Bs + (size_t)chunk * 8) = vo;
        }
        __syncthreads();
        hv8 af[4], bfr[4];
#pragma unroll
        for (int mi = 0; mi < 4; ++mi)
            af[mi] = *(const hv8*)(As + (size_t)(wm + mi * 16 + lr) * 32 + lk * 8);
#pragma unroll
        for (int ni = 0; ni < 4; ++ni)
            bfr[ni] = *(const hv8*)(Bs + (size_t)(wn + ni * 16 + lr) * 32 + lk * 8);
#pragma unroll
        for (int mi = 0; mi < 4; ++mi)
#pragma unroll
            for (int ni = 0; ni < 4; ++ni)
                acc[mi][ni] = __builtin_amdgcn_mfma_f32_16x16x32_f16(af[mi], bfr[ni], acc[mi][ni], 0, 0, 0);
        __syncthreads();
    }
#pragma unroll
    for (int mi = 0; mi < 4; ++mi)
#pragma unroll
        for (int ni = 0; ni < 4; ++ni)
#pragma unroll
            for (int r = 0; r < 4; ++r) {
                int row = m0 + wm + mi * 16 + lk * 4 + r;
                int col = n0 + wn + ni * 16 + lr;
                long idx = (long)row * NPIX + col;
                D[(long)b * NPIX * CDIM + idx] =
                    acc[mi][ni][r] + bias[row] + resid[(long)b * NPIX * CDIM + idx];
            }
}

// ---------------- flash attention v11 (champion, unchanged) ----------------
__launch_bounds__(512, 2)
__global__ void attn_kernel(const _Float16* __restrict__ qT, const _Float16* __restrict__ kT,
                            const _Float16* __restrict__ v,
                            _Float16* __restrict__ p0, _Float16* __restrict__ p1,
                            float* __restrict__ lbuf) {
    __shared__ __align__(16) _Float16 Ks[2][32 * 512];   // 64 KB, rows 1 KB, XOR (j&7)<<4
    __shared__ __align__(16) char ps[2][64 * 80];        // 10 KB, 80 B rows
    __shared__ float red[8][64];
    __shared__ float redt[64];

    const int g = blockIdx.x;
    const int xcd = g & 7;
    const int comb = xcd >> 1;                       // (batch, jhalf)
    const int itile = ((g >> 3) << 1) | (xcd & 1);   // 0..63
    const int batch = comb >> 1;
    const int jhalf = comb & 1;
    const int i0 = itile * 64;
    const int jbase = jhalf * 2048;

    const int tid = threadIdx.x;
    const int l = tid & 63, w = tid >> 6;
    const int lr = l & 15, lk = l >> 4;
    const int iq = w >> 1, jq = w & 1;               // QK: rows iq*16, cols jq*16

    const _Float16* qb = qT + (long)batch * NPIX * CDIM;
    const _Float16* kb = kT + (long)batch * NPIX * CDIM;
    const _Float16* vb = v  + (long)batch * CDIM * NPIX;

    hv8 af[16];
    {
        const _Float16* qr = qb + (long)(i0 + iq * 16 + lr) * CDIM + lk * 8;
#pragma unroll
        for (int kk = 0; kk < 16; ++kk)
            af[kk] = *(const hv8*)(qr + kk * 32);
    }

    f32x4 oacc[4][4] = {};
    float lsum[4] = {};
    hv8 vf[4];

    const _Float16* vptr = vb + (long)(w * 64 + lr) * NPIX + jbase + lk * 8;
    const float scale = 0.044194173824159216f;   // 1/sqrt(512)

#define STAGE(BUF, JT)                                                               \
    {                                                                                \
        const long j0s = (long)jbase + (JT) * 32;                                    \
        _Float16* kd = Ks[BUF];                                                      \
        _Pragma("unroll")                                                            \
        for (int q = 0; q < 4; ++q) {                                                \
            int row = q * 8 + w;                                                     \
            int cc = l ^ (row & 7);                                                  \
            lds_direct16(kb + (j0s + row) * CDIM + cc * 8, kd + row * 512);          \
        }                                                                            \
    }

#define VLOAD(JT)                                                                    \
    {                                                                                \
        _Pragma("unroll")                                                            \
        for (int ni = 0; ni < 4; ++ni)                                               \
            vf[ni] = *(const hv8*)(vptr + (long)ni * (16 * NPIX) + (JT) * 32);       \
    }

#define QKEXP(CUR)                                                                   \
    {                                                                                \
        const char* kbase = (const char*)Ks[CUR];                                    \
        f32x4 sa = {}, sb = {};                                                      \
        const int jj = jq * 16 + lr;                                                 \
        const uint32_t sw = (uint32_t)((jj & 7) << 4);                               \
        _Pragma("unroll")                                                            \
        for (int kk = 0; kk < 8; ++kk) {                                             \
            hv8 b0 = *(const hv8*)(kbase + (((uint32_t)(jj * 1024 + (2 * kk) * 64 + lk * 16)) ^ sw));     \
            sa = __builtin_amdgcn_mfma_f32_16x16x32_f16(af[2 * kk], b0, sa, 0, 0, 0);                     \
            hv8 b1 = *(const hv8*)(kbase + (((uint32_t)(jj * 1024 + (2 * kk + 1) * 64 + lk * 16)) ^ sw)); \
            sb = __builtin_amdgcn_mfma_f32_16x16x32_f16(af[2 * kk + 1], b1, sb, 0, 0, 0);                 \
        }                                                                            \
        sa += sb;                                                                    \
        _Pragma("unroll")                                                            \
        for (int r = 0; r < 4; ++r) {                                                \
            float p = __expf(sa[r] * scale);                                         \
            lsum[r] += p;                                                            \
            int i = iq * 16 + lk * 4 + r;                                            \
            int j2 = jq * 16 + lr;                                                   \
            *(_Float16*)(ps[CUR] + i * 80 + j2 * 2) = (_Float16)p;                   \
        }                                                                            \
    }

#define PVSTEP(PRV)                                                                  \
    {                                                                                \
        _Pragma("unroll")                                                            \
        for (int mi = 0; mi < 4; ++mi) {                                             \
            int i2 = mi * 16 + lr;                                                   \
            hv8 pa = *(const hv8*)(ps[PRV] + i2 * 80 + lk * 16);                     \
            _Pragma("unroll")                                                        \
            for (int ni = 0; ni < 4; ++ni)                                           \
                oacc[mi][ni] = __builtin_amdgcn_mfma_f32_16x16x32_f16(pa, vf[ni], oacc[mi][ni], 0, 0, 0); \
        }                                                                            \
    }

#define ENDBAR(N)                                                                    \
    __builtin_amdgcn_sched_barrier(0);                                               \
    asm volatile("s_waitcnt vmcnt(" #N ") lgkmcnt(0)" ::: "memory");                 \
    __builtin_amdgcn_s_barrier();                                                    \
    __builtin_amdgcn_sched_barrier(0);

#define STEP(JT, CUR)                                                                \
    {                                                                                \
        if ((JT) < 63) STAGE((CUR) ^ 1, (JT) + 1)                                    \
        __builtin_amdgcn_sched_barrier(0);                                           \
        __builtin_amdgcn_s_setprio(1);                                               \
        QKEXP(CUR)                                                                   \
        PVSTEP((CUR) ^ 1)                                                            \
        __builtin_amdgcn_s_setprio(0);                                               \
        __builtin_amdgcn_sched_barrier(0);                                           \
        VLOAD(JT)                                                                    \
        ENDBAR(4)                                                                    \
    }

    STAGE(0, 0)
    __builtin_amdgcn_sched_barrier(0);
    asm volatile("s_waitcnt vmcnt(0)" ::: "memory");
    __builtin_amdgcn_s_barrier();
    __builtin_amdgcn_sched_barrier(0);

    STAGE(1, 1)
    __builtin_amdgcn_s_setprio(1);
    QKEXP(0)
    __builtin_amdgcn_s_setprio(0);
    VLOAD(0)
    ENDBAR(4)

    for (int jt = 1; jt < 63; jt += 2) {
        STEP(jt,     1)
        STEP(jt + 1, 0)
    }
    STEP(63, 1)

    asm volatile("s_waitcnt vmcnt(0)" ::: "memory");
    __builtin_amdgcn_sched_barrier(0);
    PVSTEP(1)

#pragma unroll
    for (int m = 1; m <= 8; m <<= 1)
#pragma unroll
        for (int r = 0; r < 4; ++r)
            lsum[r] += __shfl_xor(lsum[r], m, 64);
    if (lr == 0)
#pragma unroll
        for (int r = 0; r < 4; ++r)
            red[w][iq * 16 + lk * 4 + r] = lsum[r];
    __syncthreads();
    if (tid < 64) {
        int iq2 = tid >> 4;
        float lv = red[iq2 * 2][tid] + red[iq2 * 2 + 1][tid];
        redt[tid] = 1.0f / lv;
        lbuf[jhalf * 8192 + batch * NPIX + i0 + tid] = lv;
    }
    __syncthreads();

    _Float16* dsth = (jhalf ? p1 : p0) + (long)batch * NPIX * CDIM;
#pragma unroll
    for (int mi = 0; mi < 4; ++mi)
#pragma unroll
        for (int r = 0; r < 4; ++r) {
            int row = mi * 16 + lk * 4 + r;
            float rv = redt[row];
#pragma unroll
            for (int ni = 0; ni < 4; ++ni) {
                int c = w * 64 + ni * 16 + lr;
                dsth[(long)(i0 + row) * CDIM + c] = (_Float16)(oacc[mi][ni][r] * rv);
            }
        }
#undef STEP
#undef ENDBAR
#undef PVSTEP
#undef QKEXP
#undef VLOAD
#undef STAGE
}

extern "C" void kernel_launch(void* const* d_in, const int* in_sizes, int n_in,
                              void* d_out, int out_size, void* d_ws, size_t ws_size,
                              hipStream_t stream) {
    const float* x     = (const float*)d_in[0];
    const float* gamma = (const float*)d_in[1];
    const float* beta  = (const float*)d_in[2];
    const float* wq    = (const float*)d_in[3];
    const float* bq    = (const float*)d_in[4];
    const float* wk    = (const float*)d_in[5];
    const float* bk    = (const float*)d_in[6];
    const float* wv    = (const float*)d_in[7];
    const float* bv    = (const float*)d_in[8];
    const float* wo    = (const float*)d_in[9];
    const float* bo    = (const float*)d_in[10];
    float* out = (float*)d_out;

    char* ws = (char*)d_ws;
    float* partS = (float*)ws;               // 512
    float* partQ = partS + 512;              // 512
    float* bqk   = partQ + 512;              // 1024
    _Float16* wqb = (_Float16*)(ws + 8192);  // wq|wk adjacent -> fused BT [1024][512]
    _Float16* wkb = wqb + 262144;
    _Float16* wvb = wkb + 262144;
    _Float16* wob = wvb + 262144;
    _Float16* hT  = wob + 262144;
    const long TSZ = (long)2 * NPIX * CDIM;
    _Float16* qT = hT + TSZ;
    _Float16* kT = qT + TSZ;                 // = qT + 2*NPIX*CDIM (EPI3 relies on this)
    _Float16* vv = kT + TSZ;
    _Float16* oT = vv + TSZ;
    float* lbuf = (float*)(oT + TSZ);        // 2 halves x 8192 rows

    // stats partials + weight conversion (fused)
    pstats_kernel<<<dim3(512), dim3(256), 0, stream>>>(
        x, partS, partQ, wq, wk, wv, wo, wqb, wkb, wvb, wob, bq, bk, bqk);
    normT_kernel<<<dim3(16, 128, 2), dim3(256), 0, stream>>>(x, partS, partQ, gamma, beta, hT);

    const long NC = (long)NPIX * CDIM;
    // fused q|k GEMM: M=4096, N=1024 (cols 0..511 -> qT, 512..1023 -> kT)
    gemm_bt_kernel<3><<<dim3(8, 32, 2), dim3(256), 0, stream>>>(
        hT, wqb, (void*)qT, bqk, NPIX, 1024, CDIM, NC, 0L, NC);
    gemm_bt_kernel<1><<<dim3(32, 4, 2), dim3(256), 0, stream>>>(
        wvb, hT, (void*)vv, bv, CDIM, NPIX, CDIM, 0L, NC, NC);

    // attention: partial jhalf0 -> oT, jhalf1 -> hT (dead), sums -> lbuf
    attn_kernel<<<dim3(256), dim3(512), 0, stream>>>(qT, kT, vv, oT, hT, lbuf);

    // final GEMM with fused combine: out = wo *bt (w0*oT + w1*hT) + bo + x
    gemm_final_kernel<<<dim3(32, 4, 2), dim3(256), 0, stream>>>(
        wob, oT, hT, lbuf, out, bo, x);
}